// Round 1
// baseline (943.540 us; speedup 1.0000x reference)
//
#include <hip/hip_runtime.h>
#include <cstddef>
#include <cstdint>

// Problem constants (match reference)
#define BATCH 2
#define SEQ 8192
#define CH 256
#define NLM 40
#define MROWS (BATCH * SEQ)   // 16384
#define INV_SCALE 0.0625f     // 1/sqrt(256)

// ---------------------------------------------------------------------------
// GEMM NT: out[m][o] = sum_k A[m][k] * W[o][k] + bias[o] (+ resid[m][o])
// A: [MROWS][256], W: [256][256] row-major (contract over columns of both).
// Tile: 128 rows x 64 cols, 256 threads, 8x4 micro-tile, K-chunks of 16.
// grid: (256/64, MROWS/128) = (4, 128)
// ---------------------------------------------------------------------------
template <bool RES>
__global__ __launch_bounds__(256) void gemm_nt(const float* __restrict__ A,
                                               const float* __restrict__ W,
                                               const float* __restrict__ bias,
                                               const float* __restrict__ resid,
                                               float* __restrict__ out) {
    __shared__ float As[16][132];  // [k][m], padded
    __shared__ float Ws[16][68];   // [k][o], padded
    const int t  = threadIdx.x;
    const int tx = t & 15;         // col group (16 x 4 cols = 64)
    const int ty = t >> 4;         // row group (16 x 8 rows = 128)
    const int o0 = blockIdx.x * 64;
    const int m0 = blockIdx.y * 128;

    float acc[8][4];
#pragma unroll
    for (int i = 0; i < 8; i++)
#pragma unroll
        for (int j = 0; j < 4; j++) acc[i][j] = 0.f;

    for (int kc = 0; kc < 256; kc += 16) {
        // Stage A tile (128 rows x 16 k), transposed into As[k][m]
#pragma unroll
        for (int u = 0; u < 2; u++) {
            int f = t + u * 256;          // 0..511
            int row = f >> 2;             // 0..127
            int k4 = (f & 3) * 4;
            const float4 a = *(const float4*)&A[(size_t)(m0 + row) * 256 + kc + k4];
            As[k4 + 0][row] = a.x; As[k4 + 1][row] = a.y;
            As[k4 + 2][row] = a.z; As[k4 + 3][row] = a.w;
        }
        // Stage W tile (64 rows x 16 k), transposed into Ws[k][o]
        {
            int row = t >> 2;             // 0..63
            int k4 = (t & 3) * 4;
            const float4 w = *(const float4*)&W[(size_t)(o0 + row) * 256 + kc + k4];
            Ws[k4 + 0][row] = w.x; Ws[k4 + 1][row] = w.y;
            Ws[k4 + 2][row] = w.z; Ws[k4 + 3][row] = w.w;
        }
        __syncthreads();
#pragma unroll
        for (int kk = 0; kk < 16; kk++) {
            const float4 aLo = *(const float4*)&As[kk][ty * 8];
            const float4 aHi = *(const float4*)&As[kk][ty * 8 + 4];
            const float4 w4  = *(const float4*)&Ws[kk][tx * 4];
            const float av[8] = {aLo.x, aLo.y, aLo.z, aLo.w, aHi.x, aHi.y, aHi.z, aHi.w};
            const float wv[4] = {w4.x, w4.y, w4.z, w4.w};
#pragma unroll
            for (int i = 0; i < 8; i++)
#pragma unroll
                for (int j = 0; j < 4; j++) acc[i][j] = fmaf(av[i], wv[j], acc[i][j]);
        }
        __syncthreads();
    }

    const float4 bb = *(const float4*)&bias[o0 + tx * 4];
#pragma unroll
    for (int i = 0; i < 8; i++) {
        const int m = m0 + ty * 8 + i;
        float4 o;
        o.x = acc[i][0] + bb.x;
        o.y = acc[i][1] + bb.y;
        o.z = acc[i][2] + bb.z;
        o.w = acc[i][3] + bb.w;
        if (RES) {
            const float4 r4 = *(const float4*)&resid[(size_t)m * 256 + o0 + tx * 4];
            o.x += r4.x; o.y += r4.y; o.z += r4.z; o.w += r4.w;
        }
        *(float4*)&out[(size_t)m * 256 + o0 + tx * 4] = o;
    }
}

// ---------------------------------------------------------------------------
// qsum[b][c] = sum_n q[b][n][c].  grid (32, B), block 256. qsum pre-zeroed.
// ---------------------------------------------------------------------------
__global__ __launch_bounds__(256) void qsum_kernel(const float* __restrict__ q,
                                                   float* __restrict__ qsum) {
    const int b = blockIdx.y;
    const int r0 = blockIdx.x * 256;
    const int t = threadIdx.x;
    const float* base = q + ((size_t)b * SEQ + r0) * 256 + t;
    float s = 0.f;
    for (int i = 0; i < 256; i++) s += base[(size_t)i * 256];
    atomicAdd(&qsum[b * 256 + t], s);
}

// ---------------------------------------------------------------------------
// score[b][m] = dot(k[b][m], qsum[b]) / 16.  One wave per row.
// grid (SEQ/4, B), block 256 (4 waves).
// ---------------------------------------------------------------------------
__global__ __launch_bounds__(256) void score_kernel(const float* __restrict__ kmat,
                                                    const float* __restrict__ qsum,
                                                    float* __restrict__ score) {
    const int b = blockIdx.y;
    const int m = blockIdx.x * 4 + (threadIdx.x >> 6);
    const int lane = threadIdx.x & 63;
    const float4 kv = *(const float4*)&kmat[((size_t)b * SEQ + m) * 256 + lane * 4];
    const float4 qs = *(const float4*)&qsum[b * 256 + lane * 4];
    float d = kv.x * qs.x + kv.y * qs.y + kv.z * qs.z + kv.w * qs.w;
#pragma unroll
    for (int off = 32; off >= 1; off >>= 1) d += __shfl_down(d, off);
    if (lane == 0) score[(size_t)b * SEQ + m] = d * INV_SCALE;
}

// ---------------------------------------------------------------------------
// Top-40 per batch + gather selected key vectors. grid (B), block 1024.
// Iterative argmax over scores held in LDS (40 iterations).
// ---------------------------------------------------------------------------
__global__ __launch_bounds__(1024) void topk_gather(const float* __restrict__ score,
                                                    const float* __restrict__ kmat,
                                                    float* __restrict__ sel) {
    const int b = blockIdx.x;
    __shared__ float s[SEQ];
    __shared__ float wv[16];
    __shared__ int   wi[16];
    __shared__ int   top[NLM];
    const int t = threadIdx.x;

    for (int j = t; j < SEQ; j += 1024) s[j] = score[(size_t)b * SEQ + j];
    __syncthreads();

    for (int it = 0; it < NLM; it++) {
        float best = -1e30f;
        int bi = 0;
#pragma unroll
        for (int j = 0; j < 8; j++) {
            const int idx = t + j * 1024;
            const float v = s[idx];
            if (v > best) { best = v; bi = idx; }
        }
#pragma unroll
        for (int off = 32; off >= 1; off >>= 1) {
            const float ov = __shfl_down(best, off);
            const int   oi = __shfl_down(bi, off);
            if (ov > best || (ov == best && oi < bi)) { best = ov; bi = oi; }
        }
        const int wid = t >> 6;
        if ((t & 63) == 0) { wv[wid] = best; wi[wid] = bi; }
        __syncthreads();
        if (t < 64) {
            best = (t < 16) ? wv[t] : -1e30f;
            bi   = (t < 16) ? wi[t] : 0;
#pragma unroll
            for (int off = 8; off >= 1; off >>= 1) {
                const float ov = __shfl_down(best, off);
                const int   oi = __shfl_down(bi, off);
                if (ov > best || (ov == best && oi < bi)) { best = ov; bi = oi; }
            }
            if (t == 0) { top[it] = bi; s[bi] = -1e30f; }
        }
        __syncthreads();
    }
    // Gather selected keys: sel[b][j][c] = k[b][top[j]][c]
    for (int f = t; f < NLM * 256; f += 1024) {
        const int j = f >> 8;
        const int c = f & 255;
        sel[(size_t)b * NLM * 256 + f] = kmat[((size_t)b * SEQ + top[j]) * 256 + c];
    }
}

// ---------------------------------------------------------------------------
// Logits + softmax helper layout: block 256 threads, 64 rows/tile.
// thread t: r = t>>2 (row), c = t&3 (landmark group, 10 landmarks each).
// ---------------------------------------------------------------------------
__device__ __forceinline__ void logits_tile(const float* __restrict__ Arow,   // base of 64-row tile
                                            const float* __restrict__ Sb,     // sel base [40][256]
                                            float As_[64][68], float St_[40][68],
                                            int t, int r, int c, float acc[10]) {
    for (int kc = 0; kc < 256; kc += 64) {
#pragma unroll
        for (int u = 0; u < 4; u++) {
            const int f = t + u * 256;       // 0..1023
            const int row = f >> 4;
            const int c4 = (f & 15) * 4;
            *(float4*)&As_[row][c4] = *(const float4*)&Arow[(size_t)row * 256 + kc + c4];
        }
#pragma unroll
        for (int u = 0; u < 3; u++) {
            const int f = t + u * 256;
            if (f < 640) {
                const int row = f >> 4;
                const int c4 = (f & 15) * 4;
                *(float4*)&St_[row][c4] = *(const float4*)&Sb[(size_t)row * 256 + kc + c4];
            }
        }
        __syncthreads();
        for (int i = 0; i < 64; i += 2) {
            const float2 a = *(const float2*)&As_[r][i];
#pragma unroll
            for (int j = 0; j < 10; j++) {
                const float2 sv = *(const float2*)&St_[c + 4 * j][i];
                acc[j] = fmaf(a.x, sv.x, acc[j]);
                acc[j] = fmaf(a.y, sv.y, acc[j]);
            }
        }
        __syncthreads();
    }
}

__device__ __forceinline__ void softmax40(float acc[10]) {
    float mx = -1e30f;
#pragma unroll
    for (int j = 0; j < 10; j++) {
        acc[j] *= INV_SCALE;
        mx = fmaxf(mx, acc[j]);
    }
    mx = fmaxf(mx, __shfl_xor(mx, 1));
    mx = fmaxf(mx, __shfl_xor(mx, 2));
    float sum = 0.f;
#pragma unroll
    for (int j = 0; j < 10; j++) {
        acc[j] = expf(acc[j] - mx);
        sum += acc[j];
    }
    sum += __shfl_xor(sum, 1);
    sum += __shfl_xor(sum, 2);
    const float inv = 1.f / sum;
#pragma unroll
    for (int j = 0; j < 10; j++) acc[j] *= inv;
}

// ---------------------------------------------------------------------------
// sim_q: simq[b][n][l] = softmax_l(q[b][n]·sel[b][l] / 16). grid (SEQ/64, B).
// ---------------------------------------------------------------------------
__global__ __launch_bounds__(256) void sim_q_kernel(const float* __restrict__ q,
                                                    const float* __restrict__ sel,
                                                    float* __restrict__ simq) {
    __shared__ float As_[64][68];
    __shared__ float St_[40][68];
    const int b = blockIdx.y;
    const int n0 = blockIdx.x * 64;
    const int t = threadIdx.x;
    const int r = t >> 2, c = t & 3;
    float acc[10];
#pragma unroll
    for (int j = 0; j < 10; j++) acc[j] = 0.f;
    logits_tile(q + ((size_t)b * SEQ + n0) * 256, sel + (size_t)b * NLM * 256,
                As_, St_, t, r, c, acc);
    softmax40(acc);
#pragma unroll
    for (int j = 0; j < 10; j++)
        simq[((size_t)b * SEQ + n0 + r) * NLM + c + 4 * j] = acc[j];
}

// ---------------------------------------------------------------------------
// sim_k fused with t accumulation: t[b][l][cc] += sum_m sim_km[m][l]*v[b][m][cc]
// grid (SEQ/128, B), 2 tiles of 64 rows per block. t pre-zeroed, atomic adds.
// ---------------------------------------------------------------------------
__global__ __launch_bounds__(256) void sim_k_kernel(const float* __restrict__ kmat,
                                                    const float* __restrict__ sel,
                                                    const float* __restrict__ v,
                                                    float* __restrict__ tmat) {
    __shared__ float As_[64][68];
    __shared__ float St_[40][68];
    __shared__ float Pm[64][40];
    const int b = blockIdx.y;
    const int base = blockIdx.x * 128;
    const int t = threadIdx.x;
    const int r = t >> 2, c = t & 3;
    const float* Sb = sel + (size_t)b * NLM * 256;

    float tac[40];
#pragma unroll
    for (int l = 0; l < 40; l++) tac[l] = 0.f;

    for (int tile = 0; tile < 2; tile++) {
        const int n0 = base + tile * 64;
        float acc[10];
#pragma unroll
        for (int j = 0; j < 10; j++) acc[j] = 0.f;
        logits_tile(kmat + ((size_t)b * SEQ + n0) * 256, Sb, As_, St_, t, r, c, acc);
        softmax40(acc);
#pragma unroll
        for (int j = 0; j < 10; j++) Pm[r][c + 4 * j] = acc[j];
        __syncthreads();
        // accumulate partial t: thread <-> column cc = t
        const float* Vb = v + ((size_t)b * SEQ + n0) * 256;
        for (int m = 0; m < 64; m++) {
            const float vv = Vb[(size_t)m * 256 + t];
#pragma unroll
            for (int j4 = 0; j4 < 10; j4++) {
                const float4 p = *(const float4*)&Pm[m][j4 * 4];  // broadcast
                tac[j4 * 4 + 0] = fmaf(p.x, vv, tac[j4 * 4 + 0]);
                tac[j4 * 4 + 1] = fmaf(p.y, vv, tac[j4 * 4 + 1]);
                tac[j4 * 4 + 2] = fmaf(p.z, vv, tac[j4 * 4 + 2]);
                tac[j4 * 4 + 3] = fmaf(p.w, vv, tac[j4 * 4 + 3]);
            }
        }
        __syncthreads();
    }
#pragma unroll
    for (int l = 0; l < 40; l++)
        atomicAdd(&tmat[(size_t)b * NLM * 256 + l * 256 + t], tac[l]);
}

// ---------------------------------------------------------------------------
// out_pre[g][cc] = sum_l simq[g][l] * t[b][l][cc].  grid (MROWS/64), block 256.
// t column cached in registers; sim rows broadcast from LDS.
// ---------------------------------------------------------------------------
__global__ __launch_bounds__(256) void out_pre_kernel(const float* __restrict__ simq,
                                                      const float* __restrict__ tmat,
                                                      float* __restrict__ outp) {
    __shared__ float Pm[64][40];
    const int g0 = blockIdx.x * 64;
    const int b = g0 >> 13;
    const int t = threadIdx.x;
    // sim rows g0..g0+63 are 2560 contiguous floats
    float* pflat = &Pm[0][0];
    for (int f = t; f < 64 * NLM; f += 256) pflat[f] = simq[(size_t)g0 * NLM + f];
    float tc[40];
#pragma unroll
    for (int l = 0; l < 40; l++) tc[l] = tmat[(size_t)b * NLM * 256 + l * 256 + t];
    __syncthreads();
    for (int m = 0; m < 64; m++) {
        float a = 0.f;
#pragma unroll
        for (int j4 = 0; j4 < 10; j4++) {
            const float4 p = *(const float4*)&Pm[m][j4 * 4];  // broadcast
            a = fmaf(p.x, tc[j4 * 4 + 0], a);
            a = fmaf(p.y, tc[j4 * 4 + 1], a);
            a = fmaf(p.z, tc[j4 * 4 + 2], a);
            a = fmaf(p.w, tc[j4 * 4 + 3], a);
        }
        outp[((size_t)g0 + m) * 256 + t] = a;
    }
}

// ---------------------------------------------------------------------------
extern "C" void kernel_launch(void* const* d_in, const int* in_sizes, int n_in,
                              void* d_out, int out_size, void* d_ws, size_t ws_size,
                              hipStream_t stream) {
    const float* query = (const float*)d_in[0];
    const float* Wq = (const float*)d_in[1];
    const float* bq = (const float*)d_in[2];
    const float* Wk = (const float*)d_in[3];
    const float* bk = (const float*)d_in[4];
    const float* Wv = (const float*)d_in[5];
    const float* bv = (const float*)d_in[6];
    const float* Wo = (const float*)d_in[7];
    const float* bo = (const float*)d_in[8];
    float* out = (float*)d_out;

    char* ws = (char*)d_ws;
    const size_t SZ_MAT = (size_t)MROWS * 256 * 4;          // 16.78 MB
    float* q    = (float*)(ws);
    float* k    = (float*)(ws + SZ_MAT);
    float* v    = (float*)(ws + 2 * SZ_MAT);
    float* outp = (float*)(ws + 3 * SZ_MAT);
    char* p = ws + 4 * SZ_MAT;
    float* simq  = (float*)p;            p += (size_t)MROWS * NLM * 4;      // 2.62 MB
    float* sel   = (float*)p;            p += (size_t)BATCH * NLM * 256 * 4;
    float* tmat  = (float*)p;            p += (size_t)BATCH * NLM * 256 * 4;
    float* qsum  = (float*)p;            p += (size_t)BATCH * 256 * 4;
    float* score = (float*)p;            p += (size_t)BATCH * SEQ * 4;
    // total ~ 70 MB; assumed <= ws_size

    hipMemsetAsync(qsum, 0, (size_t)BATCH * 256 * 4, stream);
    hipMemsetAsync(tmat, 0, (size_t)BATCH * NLM * 256 * 4, stream);

    const dim3 blk(256);
    const dim3 ggrid(4, MROWS / 128);
    gemm_nt<false><<<ggrid, blk, 0, stream>>>(query, Wq, bq, nullptr, q);
    gemm_nt<false><<<ggrid, blk, 0, stream>>>(query, Wk, bk, nullptr, k);
    gemm_nt<false><<<ggrid, blk, 0, stream>>>(query, Wv, bv, nullptr, v);

    qsum_kernel<<<dim3(SEQ / 256, BATCH), blk, 0, stream>>>(q, qsum);
    score_kernel<<<dim3(SEQ / 4, BATCH), blk, 0, stream>>>(k, qsum, score);
    topk_gather<<<dim3(BATCH), dim3(1024), 0, stream>>>(score, k, sel);

    sim_q_kernel<<<dim3(SEQ / 64, BATCH), blk, 0, stream>>>(q, sel, simq);
    sim_k_kernel<<<dim3(SEQ / 128, BATCH), blk, 0, stream>>>(k, sel, v, tmat);

    out_pre_kernel<<<dim3(MROWS / 64), blk, 0, stream>>>(simq, tmat, outp);
    gemm_nt<true><<<ggrid, blk, 0, stream>>>(outp, Wo, bo, query, out);
}

// Round 3
// 828.380 us; speedup vs baseline: 1.1390x; 1.1390x over previous
//
#include <hip/hip_runtime.h>
#include <cstddef>
#include <cstdint>

// Problem constants (match reference)
#define BATCH 2
#define SEQ 8192
#define CH 256
#define NLM 40
#define MROWS (BATCH * SEQ)   // 16384
#define INV_SCALE 0.0625f     // 1/sqrt(256)

// ---------------------------------------------------------------------------
// GEMM NT: out[m][o] = sum_k A[m][k] * W[o][k] + bias[o] (+ resid[m][o])
// A: [MROWS][256], W: [256][256] row-major (contract over columns of both).
// Tile: 128 rows x 64 cols, 256 threads, 8x4 micro-tile, K-chunks of 16.
// grid: (256/64, MROWS/128) = (4, 128)
// ---------------------------------------------------------------------------
template <bool RES>
__global__ __launch_bounds__(256) void gemm_nt(const float* __restrict__ A,
                                               const float* __restrict__ W,
                                               const float* __restrict__ bias,
                                               const float* __restrict__ resid,
                                               float* __restrict__ out) {
    __shared__ float As[16][132];  // [k][m], padded
    __shared__ float Ws[16][68];   // [k][o], padded
    const int t  = threadIdx.x;
    const int tx = t & 15;         // col group (16 x 4 cols = 64)
    const int ty = t >> 4;         // row group (16 x 8 rows = 128)
    const int o0 = blockIdx.x * 64;
    const int m0 = blockIdx.y * 128;

    float acc[8][4];
#pragma unroll
    for (int i = 0; i < 8; i++)
#pragma unroll
        for (int j = 0; j < 4; j++) acc[i][j] = 0.f;

    for (int kc = 0; kc < 256; kc += 16) {
        // Stage A tile (128 rows x 16 k), transposed into As[k][m]
#pragma unroll
        for (int u = 0; u < 2; u++) {
            int f = t + u * 256;          // 0..511
            int row = f >> 2;             // 0..127
            int k4 = (f & 3) * 4;
            const float4 a = *(const float4*)&A[(size_t)(m0 + row) * 256 + kc + k4];
            As[k4 + 0][row] = a.x; As[k4 + 1][row] = a.y;
            As[k4 + 2][row] = a.z; As[k4 + 3][row] = a.w;
        }
        // Stage W tile (64 rows x 16 k), transposed into Ws[k][o]
        {
            int row = t >> 2;             // 0..63
            int k4 = (t & 3) * 4;
            const float4 w = *(const float4*)&W[(size_t)(o0 + row) * 256 + kc + k4];
            Ws[k4 + 0][row] = w.x; Ws[k4 + 1][row] = w.y;
            Ws[k4 + 2][row] = w.z; Ws[k4 + 3][row] = w.w;
        }
        __syncthreads();
#pragma unroll
        for (int kk = 0; kk < 16; kk++) {
            const float4 aLo = *(const float4*)&As[kk][ty * 8];
            const float4 aHi = *(const float4*)&As[kk][ty * 8 + 4];
            const float4 w4  = *(const float4*)&Ws[kk][tx * 4];
            const float av[8] = {aLo.x, aLo.y, aLo.z, aLo.w, aHi.x, aHi.y, aHi.z, aHi.w};
            const float wv[4] = {w4.x, w4.y, w4.z, w4.w};
#pragma unroll
            for (int i = 0; i < 8; i++)
#pragma unroll
                for (int j = 0; j < 4; j++) acc[i][j] = fmaf(av[i], wv[j], acc[i][j]);
        }
        __syncthreads();
    }

    const float4 bb = *(const float4*)&bias[o0 + tx * 4];
#pragma unroll
    for (int i = 0; i < 8; i++) {
        const int m = m0 + ty * 8 + i;
        float4 o;
        o.x = acc[i][0] + bb.x;
        o.y = acc[i][1] + bb.y;
        o.z = acc[i][2] + bb.z;
        o.w = acc[i][3] + bb.w;
        if (RES) {
            const float4 r4 = *(const float4*)&resid[(size_t)m * 256 + o0 + tx * 4];
            o.x += r4.x; o.y += r4.y; o.z += r4.z; o.w += r4.w;
        }
        *(float4*)&out[(size_t)m * 256 + o0 + tx * 4] = o;
    }
}

// ---------------------------------------------------------------------------
// qsum[b][c] = sum_n q[b][n][c].  grid (32, B), block 256. qsum pre-zeroed.
// ---------------------------------------------------------------------------
__global__ __launch_bounds__(256) void qsum_kernel(const float* __restrict__ q,
                                                   float* __restrict__ qsum) {
    const int b = blockIdx.y;
    const int r0 = blockIdx.x * 256;
    const int t = threadIdx.x;
    const float* base = q + ((size_t)b * SEQ + r0) * 256 + t;
    float s = 0.f;
    for (int i = 0; i < 256; i++) s += base[(size_t)i * 256];
    atomicAdd(&qsum[b * 256 + t], s);
}

// ---------------------------------------------------------------------------
// score[b][m] = dot(k[b][m], qsum[b]) / 16.  One wave per row.
// grid (SEQ/4, B), block 256 (4 waves).
// ---------------------------------------------------------------------------
__global__ __launch_bounds__(256) void score_kernel(const float* __restrict__ kmat,
                                                    const float* __restrict__ qsum,
                                                    float* __restrict__ score) {
    const int b = blockIdx.y;
    const int m = blockIdx.x * 4 + (threadIdx.x >> 6);
    const int lane = threadIdx.x & 63;
    const float4 kv = *(const float4*)&kmat[((size_t)b * SEQ + m) * 256 + lane * 4];
    const float4 qs = *(const float4*)&qsum[b * 256 + lane * 4];
    float d = kv.x * qs.x + kv.y * qs.y + kv.z * qs.z + kv.w * qs.w;
#pragma unroll
    for (int off = 32; off >= 1; off >>= 1) d += __shfl_down(d, off);
    if (lane == 0) score[(size_t)b * SEQ + m] = d * INV_SCALE;
}

// ---------------------------------------------------------------------------
// Top-40 per batch + gather selected key vectors. grid (B), block 1024.
// Iterative argmax over scores held in LDS (40 iterations).
// ---------------------------------------------------------------------------
__global__ __launch_bounds__(1024) void topk_gather(const float* __restrict__ score,
                                                    const float* __restrict__ kmat,
                                                    float* __restrict__ sel) {
    const int b = blockIdx.x;
    __shared__ float s[SEQ];
    __shared__ float wv[16];
    __shared__ int   wi[16];
    __shared__ int   top[NLM];
    const int t = threadIdx.x;

    for (int j = t; j < SEQ; j += 1024) s[j] = score[(size_t)b * SEQ + j];
    __syncthreads();

    for (int it = 0; it < NLM; it++) {
        float best = -1e30f;
        int bi = 0;
#pragma unroll
        for (int j = 0; j < 8; j++) {
            const int idx = t + j * 1024;
            const float v = s[idx];
            if (v > best) { best = v; bi = idx; }
        }
#pragma unroll
        for (int off = 32; off >= 1; off >>= 1) {
            const float ov = __shfl_down(best, off);
            const int   oi = __shfl_down(bi, off);
            if (ov > best || (ov == best && oi < bi)) { best = ov; bi = oi; }
        }
        const int wid = t >> 6;
        if ((t & 63) == 0) { wv[wid] = best; wi[wid] = bi; }
        __syncthreads();
        if (t < 64) {
            best = (t < 16) ? wv[t] : -1e30f;
            bi   = (t < 16) ? wi[t] : 0;
#pragma unroll
            for (int off = 8; off >= 1; off >>= 1) {
                const float ov = __shfl_down(best, off);
                const int   oi = __shfl_down(bi, off);
                if (ov > best || (ov == best && oi < bi)) { best = ov; bi = oi; }
            }
            if (t == 0) { top[it] = bi; s[bi] = -1e30f; }
        }
        __syncthreads();
    }
    // Gather selected keys: sel[b][j][c] = k[b][top[j]][c]
    for (int f = t; f < NLM * 256; f += 1024) {
        const int j = f >> 8;
        const int c = f & 255;
        sel[(size_t)b * NLM * 256 + f] = kmat[((size_t)b * SEQ + top[j]) * 256 + c];
    }
}

// ---------------------------------------------------------------------------
// Logits + softmax helper layout: block 256 threads, 64 rows/tile.
// thread t: r = t>>2 (row), c = t&3 (landmark group, 10 landmarks each).
// ---------------------------------------------------------------------------
__device__ __forceinline__ void logits_tile(const float* __restrict__ Arow,   // base of 64-row tile
                                            const float* __restrict__ Sb,     // sel base [40][256]
                                            float As_[64][68], float St_[40][68],
                                            int t, int r, int c, float acc[10]) {
    for (int kc = 0; kc < 256; kc += 64) {
#pragma unroll
        for (int u = 0; u < 4; u++) {
            const int f = t + u * 256;       // 0..1023
            const int row = f >> 4;
            const int c4 = (f & 15) * 4;
            *(float4*)&As_[row][c4] = *(const float4*)&Arow[(size_t)row * 256 + kc + c4];
        }
#pragma unroll
        for (int u = 0; u < 3; u++) {
            const int f = t + u * 256;
            if (f < 640) {
                const int row = f >> 4;
                const int c4 = (f & 15) * 4;
                *(float4*)&St_[row][c4] = *(const float4*)&Sb[(size_t)row * 256 + kc + c4];
            }
        }
        __syncthreads();
        for (int i = 0; i < 64; i += 2) {
            const float2 a = *(const float2*)&As_[r][i];
#pragma unroll
            for (int j = 0; j < 10; j++) {
                const float2 sv = *(const float2*)&St_[c + 4 * j][i];
                acc[j] = fmaf(a.x, sv.x, acc[j]);
                acc[j] = fmaf(a.y, sv.y, acc[j]);
            }
        }
        __syncthreads();
    }
}

__device__ __forceinline__ void softmax40(float acc[10]) {
    float mx = -1e30f;
#pragma unroll
    for (int j = 0; j < 10; j++) {
        acc[j] *= INV_SCALE;
        mx = fmaxf(mx, acc[j]);
    }
    mx = fmaxf(mx, __shfl_xor(mx, 1));
    mx = fmaxf(mx, __shfl_xor(mx, 2));
    float sum = 0.f;
#pragma unroll
    for (int j = 0; j < 10; j++) {
        acc[j] = expf(acc[j] - mx);
        sum += acc[j];
    }
    sum += __shfl_xor(sum, 1);
    sum += __shfl_xor(sum, 2);
    const float inv = 1.f / sum;
#pragma unroll
    for (int j = 0; j < 10; j++) acc[j] *= inv;
}

// ---------------------------------------------------------------------------
// sim softmax: sim[b][n][l] = softmax_l(A[b][n]·sel[b][l] / 16). grid (SEQ/64, B).
// Used for both sim_qn (A=q) and sim_km (A=k).
// ---------------------------------------------------------------------------
__global__ __launch_bounds__(256) void sim_softmax_kernel(const float* __restrict__ A,
                                                          const float* __restrict__ sel,
                                                          float* __restrict__ sim) {
    __shared__ float As_[64][68];
    __shared__ float St_[40][68];
    const int b = blockIdx.y;
    const int n0 = blockIdx.x * 64;
    const int t = threadIdx.x;
    const int r = t >> 2, c = t & 3;
    float acc[10];
#pragma unroll
    for (int j = 0; j < 10; j++) acc[j] = 0.f;
    logits_tile(A + ((size_t)b * SEQ + n0) * 256, sel + (size_t)b * NLM * 256,
                As_, St_, t, r, c, acc);
    softmax40(acc);
#pragma unroll
    for (int j = 0; j < 10; j++)
        sim[((size_t)b * SEQ + n0 + r) * NLM + c + 4 * j] = acc[j];
}

// ---------------------------------------------------------------------------
// tmat_kernel: t[b][l][cc] = sum_m simk[b][m][l] * v[b][m][cc]
// Split-K reduction GEMM. grid (SEQ/128, 4, B): block covers 128 rows and a
// group of 10 landmarks; thread t owns channel column cc = t. Only tac[10]
// accumulators -> no VGPR spill. tmat pre-zeroed; partials via atomicAdd
// (64 adds per location).
// ---------------------------------------------------------------------------
__global__ __launch_bounds__(256) void tmat_kernel(const float* __restrict__ simk,
                                                   const float* __restrict__ v,
                                                   float* __restrict__ tmat) {
    __shared__ float Ps[128][12];  // 10 landmarks, padded to 12 (keeps 16B align)
    const int b  = blockIdx.z;
    const int lg = blockIdx.y;     // landmark group: lm = lg*10 .. lg*10+9
    const int n0 = blockIdx.x * 128;
    const int t  = threadIdx.x;

    // Stage simk slice [128 rows][10 lm] into LDS
    for (int f = t; f < 128 * 10; f += 256) {
        const int row = f / 10;
        const int l   = f - row * 10;
        Ps[row][l] = simk[((size_t)b * SEQ + n0 + row) * NLM + lg * 10 + l];
    }
    __syncthreads();

    float tac[10];
#pragma unroll
    for (int j = 0; j < 10; j++) tac[j] = 0.f;

    const float* Vb = v + ((size_t)b * SEQ + n0) * 256 + t;
#pragma unroll 4
    for (int m = 0; m < 128; m++) {
        const float vv = Vb[(size_t)m * 256];
        const float4 p0 = *(const float4*)&Ps[m][0];  // LDS broadcast reads
        const float4 p1 = *(const float4*)&Ps[m][4];
        const float2 p2 = *(const float2*)&Ps[m][8];
        tac[0] = fmaf(p0.x, vv, tac[0]);
        tac[1] = fmaf(p0.y, vv, tac[1]);
        tac[2] = fmaf(p0.z, vv, tac[2]);
        tac[3] = fmaf(p0.w, vv, tac[3]);
        tac[4] = fmaf(p1.x, vv, tac[4]);
        tac[5] = fmaf(p1.y, vv, tac[5]);
        tac[6] = fmaf(p1.z, vv, tac[6]);
        tac[7] = fmaf(p1.w, vv, tac[7]);
        tac[8] = fmaf(p2.x, vv, tac[8]);
        tac[9] = fmaf(p2.y, vv, tac[9]);
    }
#pragma unroll
    for (int j = 0; j < 10; j++)
        atomicAdd(&tmat[(size_t)b * NLM * 256 + (lg * 10 + j) * 256 + t], tac[j]);
}

// ---------------------------------------------------------------------------
// out_pre[g][cc] = sum_l simq[g][l] * t[b][l][cc].  grid (MROWS/64), block 256.
// t column cached in registers; sim rows broadcast from LDS.
// ---------------------------------------------------------------------------
__global__ __launch_bounds__(256) void out_pre_kernel(const float* __restrict__ simq,
                                                      const float* __restrict__ tmat,
                                                      float* __restrict__ outp) {
    __shared__ float Pm[64][40];
    const int g0 = blockIdx.x * 64;
    const int b = g0 >> 13;
    const int t = threadIdx.x;
    // sim rows g0..g0+63 are 2560 contiguous floats
    float* pflat = &Pm[0][0];
    for (int f = t; f < 64 * NLM; f += 256) pflat[f] = simq[(size_t)g0 * NLM + f];
    float tc[40];
#pragma unroll
    for (int l = 0; l < 40; l++) tc[l] = tmat[(size_t)b * NLM * 256 + l * 256 + t];
    __syncthreads();
    for (int m = 0; m < 64; m++) {
        float a = 0.f;
#pragma unroll
        for (int j4 = 0; j4 < 10; j4++) {
            const float4 p = *(const float4*)&Pm[m][j4 * 4];  // broadcast
            a = fmaf(p.x, tc[j4 * 4 + 0], a);
            a = fmaf(p.y, tc[j4 * 4 + 1], a);
            a = fmaf(p.z, tc[j4 * 4 + 2], a);
            a = fmaf(p.w, tc[j4 * 4 + 3], a);
        }
        outp[((size_t)g0 + m) * 256 + t] = a;
    }
}

// ---------------------------------------------------------------------------
// Workspace layout (total ~55.8 MB — well under the R1-proven-safe ~70 MB):
//   smalls first:  simq, simk, sel, tmat, qsum, score   (~5.5 MB)
//   then big mats: q, k, v                              (3 x 16.78 MB)
//   outp ALIASES q: q is dead after sim_softmax(q); out_pre runs after.
// R2's post-timing corruption is attributed to d_ws overflow (R2 layout grew
// past the watermark); keep total footprint small and smalls up front.
// ---------------------------------------------------------------------------
extern "C" void kernel_launch(void* const* d_in, const int* in_sizes, int n_in,
                              void* d_out, int out_size, void* d_ws, size_t ws_size,
                              hipStream_t stream) {
    const float* query = (const float*)d_in[0];
    const float* Wq = (const float*)d_in[1];
    const float* bq = (const float*)d_in[2];
    const float* Wk = (const float*)d_in[3];
    const float* bk = (const float*)d_in[4];
    const float* Wv = (const float*)d_in[5];
    const float* bv = (const float*)d_in[6];
    const float* Wo = (const float*)d_in[7];
    const float* bo = (const float*)d_in[8];
    float* out = (float*)d_out;

    char* p = (char*)d_ws;
    const size_t SZ_MAT = (size_t)MROWS * 256 * 4;          // 16.78 MB
    float* simq  = (float*)p;            p += (size_t)MROWS * NLM * 4;      // 2.62 MB
    float* simk  = (float*)p;            p += (size_t)MROWS * NLM * 4;      // 2.62 MB
    float* sel   = (float*)p;            p += (size_t)BATCH * NLM * 256 * 4;
    float* tmat  = (float*)p;            p += (size_t)BATCH * NLM * 256 * 4;
    float* qsum  = (float*)p;            p += (size_t)BATCH * 256 * 4;
    float* score = (float*)p;            p += (size_t)BATCH * SEQ * 4;
    float* q     = (float*)p;            p += SZ_MAT;
    float* k     = (float*)p;            p += SZ_MAT;
    float* v     = (float*)p;            p += SZ_MAT;
    float* outp  = q;   // alias: q is dead before out_pre_kernel runs

    hipMemsetAsync(qsum, 0, (size_t)BATCH * 256 * 4, stream);
    hipMemsetAsync(tmat, 0, (size_t)BATCH * NLM * 256 * 4, stream);

    const dim3 blk(256);
    const dim3 ggrid(4, MROWS / 128);
    gemm_nt<false><<<ggrid, blk, 0, stream>>>(query, Wq, bq, nullptr, q);
    gemm_nt<false><<<ggrid, blk, 0, stream>>>(query, Wk, bk, nullptr, k);
    gemm_nt<false><<<ggrid, blk, 0, stream>>>(query, Wv, bv, nullptr, v);

    qsum_kernel<<<dim3(SEQ / 256, BATCH), blk, 0, stream>>>(q, qsum);
    score_kernel<<<dim3(SEQ / 4, BATCH), blk, 0, stream>>>(k, qsum, score);
    topk_gather<<<dim3(BATCH), dim3(1024), 0, stream>>>(score, k, sel);

    sim_softmax_kernel<<<dim3(SEQ / 64, BATCH), blk, 0, stream>>>(q, sel, simq);
    sim_softmax_kernel<<<dim3(SEQ / 64, BATCH), blk, 0, stream>>>(k, sel, simk);
    tmat_kernel<<<dim3(SEQ / 128, 4, BATCH), blk, 0, stream>>>(simk, v, tmat);

    // out_pre writes outp (aliased onto q) — q is no longer read after simq
    out_pre_kernel<<<dim3(MROWS / 64), blk, 0, stream>>>(simq, tmat, outp);
    gemm_nt<true><<<ggrid, blk, 0, stream>>>(outp, Wo, bo, query, out);
}

// Round 4
// 360.839 us; speedup vs baseline: 2.6148x; 2.2957x over previous
//
#include <hip/hip_runtime.h>
#include <cstddef>
#include <cstdint>

// Problem constants (match reference)
#define BATCH 2
#define SEQ 8192
#define CH 256
#define NLM 40
#define MROWS (BATCH * SEQ)   // 16384
#define INV_SCALE 0.0625f     // 1/sqrt(256)

// ---------------------------------------------------------------------------
// GEMM NT: out[m][o] = sum_k A[m][k] * W[o][k] + bias[o] (+ resid[m][o])
// A: [MROWS][256], W: [256][256] row-major (contract over columns of both).
// Tile: 128 rows x 64 cols, 256 threads, 8x4 micro-tile, K-chunks of 16.
// grid: (256/64, MROWS/128) = (4, 128)
// ---------------------------------------------------------------------------
template <bool RES>
__global__ __launch_bounds__(256) void gemm_nt(const float* __restrict__ A,
                                               const float* __restrict__ W,
                                               const float* __restrict__ bias,
                                               const float* __restrict__ resid,
                                               float* __restrict__ out) {
    __shared__ float As[16][132];  // [k][m], padded
    __shared__ float Ws[16][68];   // [k][o], padded
    const int t  = threadIdx.x;
    const int tx = t & 15;         // col group (16 x 4 cols = 64)
    const int ty = t >> 4;         // row group (16 x 8 rows = 128)
    const int o0 = blockIdx.x * 64;
    const int m0 = blockIdx.y * 128;

    float acc[8][4];
#pragma unroll
    for (int i = 0; i < 8; i++)
#pragma unroll
        for (int j = 0; j < 4; j++) acc[i][j] = 0.f;

    for (int kc = 0; kc < 256; kc += 16) {
        // Stage A tile (128 rows x 16 k), transposed into As[k][m]
#pragma unroll
        for (int u = 0; u < 2; u++) {
            int f = t + u * 256;          // 0..511
            int row = f >> 2;             // 0..127
            int k4 = (f & 3) * 4;
            const float4 a = *(const float4*)&A[(size_t)(m0 + row) * 256 + kc + k4];
            As[k4 + 0][row] = a.x; As[k4 + 1][row] = a.y;
            As[k4 + 2][row] = a.z; As[k4 + 3][row] = a.w;
        }
        // Stage W tile (64 rows x 16 k), transposed into Ws[k][o]
        {
            int row = t >> 2;             // 0..63
            int k4 = (t & 3) * 4;
            const float4 w = *(const float4*)&W[(size_t)(o0 + row) * 256 + kc + k4];
            Ws[k4 + 0][row] = w.x; Ws[k4 + 1][row] = w.y;
            Ws[k4 + 2][row] = w.z; Ws[k4 + 3][row] = w.w;
        }
        __syncthreads();
#pragma unroll
        for (int kk = 0; kk < 16; kk++) {
            const float4 aLo = *(const float4*)&As[kk][ty * 8];
            const float4 aHi = *(const float4*)&As[kk][ty * 8 + 4];
            const float4 w4  = *(const float4*)&Ws[kk][tx * 4];
            const float av[8] = {aLo.x, aLo.y, aLo.z, aLo.w, aHi.x, aHi.y, aHi.z, aHi.w};
            const float wv[4] = {w4.x, w4.y, w4.z, w4.w};
#pragma unroll
            for (int i = 0; i < 8; i++)
#pragma unroll
                for (int j = 0; j < 4; j++) acc[i][j] = fmaf(av[i], wv[j], acc[i][j]);
        }
        __syncthreads();
    }

    const float4 bb = *(const float4*)&bias[o0 + tx * 4];
#pragma unroll
    for (int i = 0; i < 8; i++) {
        const int m = m0 + ty * 8 + i;
        float4 o;
        o.x = acc[i][0] + bb.x;
        o.y = acc[i][1] + bb.y;
        o.z = acc[i][2] + bb.z;
        o.w = acc[i][3] + bb.w;
        if (RES) {
            const float4 r4 = *(const float4*)&resid[(size_t)m * 256 + o0 + tx * 4];
            o.x += r4.x; o.y += r4.y; o.z += r4.z; o.w += r4.w;
        }
        *(float4*)&out[(size_t)m * 256 + o0 + tx * 4] = o;
    }
}

// ---------------------------------------------------------------------------
// qsum[b][c] = sum_n q[b][n][c].  grid (32, B), block 256. qsum pre-zeroed.
// ---------------------------------------------------------------------------
__global__ __launch_bounds__(256) void qsum_kernel(const float* __restrict__ q,
                                                   float* __restrict__ qsum) {
    const int b = blockIdx.y;
    const int r0 = blockIdx.x * 256;
    const int t = threadIdx.x;
    const float* base = q + ((size_t)b * SEQ + r0) * 256 + t;
    float s = 0.f;
    for (int i = 0; i < 256; i++) s += base[(size_t)i * 256];
    atomicAdd(&qsum[b * 256 + t], s);
}

// ---------------------------------------------------------------------------
// score[b][m] = dot(k[b][m], qsum[b]) / 16.  One wave per row.
// grid (SEQ/4, B), block 256 (4 waves).
// ---------------------------------------------------------------------------
__global__ __launch_bounds__(256) void score_kernel(const float* __restrict__ kmat,
                                                    const float* __restrict__ qsum,
                                                    float* __restrict__ score) {
    const int b = blockIdx.y;
    const int m = blockIdx.x * 4 + (threadIdx.x >> 6);
    const int lane = threadIdx.x & 63;
    const float4 kv = *(const float4*)&kmat[((size_t)b * SEQ + m) * 256 + lane * 4];
    const float4 qs = *(const float4*)&qsum[b * 256 + lane * 4];
    float d = kv.x * qs.x + kv.y * qs.y + kv.z * qs.z + kv.w * qs.w;
#pragma unroll
    for (int off = 32; off >= 1; off >>= 1) d += __shfl_down(d, off);
    if (lane == 0) score[(size_t)b * SEQ + m] = d * INV_SCALE;
}

// ---------------------------------------------------------------------------
// Top-40 per batch + gather selected key vectors. grid (B), block 1024.
// Iterative argmax over scores held in LDS (40 iterations).
// ---------------------------------------------------------------------------
__global__ __launch_bounds__(1024) void topk_gather(const float* __restrict__ score,
                                                    const float* __restrict__ kmat,
                                                    float* __restrict__ sel) {
    const int b = blockIdx.x;
    __shared__ float s[SEQ];
    __shared__ float wv[16];
    __shared__ int   wi[16];
    __shared__ int   top[NLM];
    const int t = threadIdx.x;

    for (int j = t; j < SEQ; j += 1024) s[j] = score[(size_t)b * SEQ + j];
    __syncthreads();

    for (int it = 0; it < NLM; it++) {
        float best = -1e30f;
        int bi = 0;
#pragma unroll
        for (int j = 0; j < 8; j++) {
            const int idx = t + j * 1024;
            const float v = s[idx];
            if (v > best) { best = v; bi = idx; }
        }
#pragma unroll
        for (int off = 32; off >= 1; off >>= 1) {
            const float ov = __shfl_down(best, off);
            const int   oi = __shfl_down(bi, off);
            if (ov > best || (ov == best && oi < bi)) { best = ov; bi = oi; }
        }
        const int wid = t >> 6;
        if ((t & 63) == 0) { wv[wid] = best; wi[wid] = bi; }
        __syncthreads();
        if (t < 64) {
            best = (t < 16) ? wv[t] : -1e30f;
            bi   = (t < 16) ? wi[t] : 0;
#pragma unroll
            for (int off = 8; off >= 1; off >>= 1) {
                const float ov = __shfl_down(best, off);
                const int   oi = __shfl_down(bi, off);
                if (ov > best || (ov == best && oi < bi)) { best = ov; bi = oi; }
            }
            if (t == 0) { top[it] = bi; s[bi] = -1e30f; }
        }
        __syncthreads();
    }
    // Gather selected keys: sel[b][j][c] = k[b][top[j]][c]
    for (int f = t; f < NLM * 256; f += 1024) {
        const int j = f >> 8;
        const int c = f & 255;
        sel[(size_t)b * NLM * 256 + f] = kmat[((size_t)b * SEQ + top[j]) * 256 + c];
    }
}

// ---------------------------------------------------------------------------
// sim softmax: sim[b][n][lm] = softmax_lm(A[b][n]·sel[b][lm] / 16).
// grid (SEQ/64, B), block 256. Thread t: row r = t>>2, landmark group c = t&3
// covering lm = c*10 .. c*10+9 (contiguous -> float2 stores).
// REGISTER-PRESSURE NOTE: R3 version spilled 13 KB/thread (VGPR=256, 420 MB
// scratch writes) because the fully-unrolled i-loop hoisted ~1400 LDS loads.
// Fix: #pragma unroll 1 on the i-loop + float4 reads + launch_bounds(256,4)
// to cap the allocator at 128 VGPRs. Live set is ~80 VGPRs.
// ---------------------------------------------------------------------------
__global__ __launch_bounds__(256, 4) void sim_softmax_kernel(const float* __restrict__ A,
                                                             const float* __restrict__ sel,
                                                             float* __restrict__ sim) {
    __shared__ float As_[64][68];
    __shared__ float St_[40][68];
    const int b = blockIdx.y;
    const int n0 = blockIdx.x * 64;
    const int t = threadIdx.x;
    const int r = t >> 2, c = t & 3;
    const float* __restrict__ Arow = A + ((size_t)b * SEQ + n0) * 256;
    const float* __restrict__ Sb = sel + (size_t)b * NLM * 256;

    float acc[10];
#pragma unroll
    for (int j = 0; j < 10; j++) acc[j] = 0.f;

    for (int kc = 0; kc < 256; kc += 64) {
        // Stage A tile (64 rows x 64 k)
#pragma unroll
        for (int u = 0; u < 4; u++) {
            const int f = t + u * 256;       // 0..1023
            const int row = f >> 4;
            const int c4 = (f & 15) * 4;
            *(float4*)&As_[row][c4] = *(const float4*)&Arow[(size_t)row * 256 + kc + c4];
        }
        // Stage sel tile (40 rows x 64 k)
#pragma unroll
        for (int u = 0; u < 3; u++) {
            const int f = t + u * 256;
            if (f < 640) {
                const int row = f >> 4;
                const int c4 = (f & 15) * 4;
                *(float4*)&St_[row][c4] = *(const float4*)&Sb[(size_t)row * 256 + kc + c4];
            }
        }
        __syncthreads();
#pragma unroll 1
        for (int i = 0; i < 64; i += 4) {
            const float4 a = *(const float4*)&As_[r][i];
#pragma unroll
            for (int j = 0; j < 10; j++) {
                const float4 s = *(const float4*)&St_[c * 10 + j][i];  // broadcast
                acc[j] = fmaf(a.x, s.x, acc[j]);
                acc[j] = fmaf(a.y, s.y, acc[j]);
                acc[j] = fmaf(a.z, s.z, acc[j]);
                acc[j] = fmaf(a.w, s.w, acc[j]);
            }
        }
        __syncthreads();
    }

    // Softmax over all 40 lm (10 here + 30 in the 3 sibling lanes c^1, c^2).
    float mx = -1e30f;
#pragma unroll
    for (int j = 0; j < 10; j++) {
        acc[j] *= INV_SCALE;
        mx = fmaxf(mx, acc[j]);
    }
    mx = fmaxf(mx, __shfl_xor(mx, 1));
    mx = fmaxf(mx, __shfl_xor(mx, 2));
    float sum = 0.f;
#pragma unroll
    for (int j = 0; j < 10; j++) {
        acc[j] = expf(acc[j] - mx);
        sum += acc[j];
    }
    sum += __shfl_xor(sum, 1);
    sum += __shfl_xor(sum, 2);
    const float inv = 1.f / sum;
#pragma unroll
    for (int j = 0; j < 10; j++) acc[j] *= inv;

    // Store 10 contiguous lm as 5 float2 (base lm = c*10, always even)
    float* __restrict__ dst = &sim[((size_t)b * SEQ + n0 + r) * NLM + c * 10];
#pragma unroll
    for (int j2 = 0; j2 < 5; j2++) {
        float2 o; o.x = acc[2 * j2]; o.y = acc[2 * j2 + 1];
        *(float2*)&dst[2 * j2] = o;
    }
}

// ---------------------------------------------------------------------------
// tmat_kernel: t[b][l][cc] = sum_m simk[b][m][l] * v[b][m][cc]
// Split-K reduction GEMM. grid (SEQ/128, 4, B): block covers 128 rows and a
// group of 10 landmarks; thread t owns channel column cc = t. Only tac[10]
// accumulators -> no VGPR spill. tmat pre-zeroed; partials via atomicAdd
// (64 adds per location).
// ---------------------------------------------------------------------------
__global__ __launch_bounds__(256) void tmat_kernel(const float* __restrict__ simk,
                                                   const float* __restrict__ v,
                                                   float* __restrict__ tmat) {
    __shared__ float Ps[128][12];  // 10 landmarks, padded to 12 (keeps 16B align)
    const int b  = blockIdx.z;
    const int lg = blockIdx.y;     // landmark group: lm = lg*10 .. lg*10+9
    const int n0 = blockIdx.x * 128;
    const int t  = threadIdx.x;

    // Stage simk slice [128 rows][10 lm] into LDS
    for (int f = t; f < 128 * 10; f += 256) {
        const int row = f / 10;
        const int l   = f - row * 10;
        Ps[row][l] = simk[((size_t)b * SEQ + n0 + row) * NLM + lg * 10 + l];
    }
    __syncthreads();

    float tac[10];
#pragma unroll
    for (int j = 0; j < 10; j++) tac[j] = 0.f;

    const float* Vb = v + ((size_t)b * SEQ + n0) * 256 + t;
#pragma unroll 4
    for (int m = 0; m < 128; m++) {
        const float vv = Vb[(size_t)m * 256];
        const float4 p0 = *(const float4*)&Ps[m][0];  // LDS broadcast reads
        const float4 p1 = *(const float4*)&Ps[m][4];
        const float2 p2 = *(const float2*)&Ps[m][8];
        tac[0] = fmaf(p0.x, vv, tac[0]);
        tac[1] = fmaf(p0.y, vv, tac[1]);
        tac[2] = fmaf(p0.z, vv, tac[2]);
        tac[3] = fmaf(p0.w, vv, tac[3]);
        tac[4] = fmaf(p1.x, vv, tac[4]);
        tac[5] = fmaf(p1.y, vv, tac[5]);
        tac[6] = fmaf(p1.z, vv, tac[6]);
        tac[7] = fmaf(p1.w, vv, tac[7]);
        tac[8] = fmaf(p2.x, vv, tac[8]);
        tac[9] = fmaf(p2.y, vv, tac[9]);
    }
#pragma unroll
    for (int j = 0; j < 10; j++)
        atomicAdd(&tmat[(size_t)b * NLM * 256 + (lg * 10 + j) * 256 + t], tac[j]);
}

// ---------------------------------------------------------------------------
// out_pre[g][cc] = sum_l simq[g][l] * t[b][l][cc].  grid (MROWS/64), block 256.
// t column cached in registers; sim rows broadcast from LDS.
// m-loop unroll bounded to 2 (same spill-risk pattern as sim_softmax).
// ---------------------------------------------------------------------------
__global__ __launch_bounds__(256) void out_pre_kernel(const float* __restrict__ simq,
                                                      const float* __restrict__ tmat,
                                                      float* __restrict__ outp) {
    __shared__ float Pm[64][40];
    const int g0 = blockIdx.x * 64;
    const int b = g0 >> 13;
    const int t = threadIdx.x;
    // sim rows g0..g0+63 are 2560 contiguous floats
    float* pflat = &Pm[0][0];
    for (int f = t; f < 64 * NLM; f += 256) pflat[f] = simq[(size_t)g0 * NLM + f];
    float tc[40];
#pragma unroll
    for (int l = 0; l < 40; l++) tc[l] = tmat[(size_t)b * NLM * 256 + l * 256 + t];
    __syncthreads();
#pragma unroll 2
    for (int m = 0; m < 64; m++) {
        float a = 0.f;
#pragma unroll
        for (int j4 = 0; j4 < 10; j4++) {
            const float4 p = *(const float4*)&Pm[m][j4 * 4];  // broadcast
            a = fmaf(p.x, tc[j4 * 4 + 0], a);
            a = fmaf(p.y, tc[j4 * 4 + 1], a);
            a = fmaf(p.z, tc[j4 * 4 + 2], a);
            a = fmaf(p.w, tc[j4 * 4 + 3], a);
        }
        outp[((size_t)g0 + m) * 256 + t] = a;
    }
}

// ---------------------------------------------------------------------------
// Workspace layout (total ~55.8 MB — R3-proven safe):
//   smalls first:  simq, simk, sel, tmat, qsum, score   (~5.5 MB)
//   then big mats: q, k, v                              (3 x 16.78 MB)
//   outp ALIASES q: q is dead after sim_softmax(q); out_pre runs after.
// ---------------------------------------------------------------------------
extern "C" void kernel_launch(void* const* d_in, const int* in_sizes, int n_in,
                              void* d_out, int out_size, void* d_ws, size_t ws_size,
                              hipStream_t stream) {
    const float* query = (const float*)d_in[0];
    const float* Wq = (const float*)d_in[1];
    const float* bq = (const float*)d_in[2];
    const float* Wk = (const float*)d_in[3];
    const float* bk = (const float*)d_in[4];
    const float* Wv = (const float*)d_in[5];
    const float* bv = (const float*)d_in[6];
    const float* Wo = (const float*)d_in[7];
    const float* bo = (const float*)d_in[8];
    float* out = (float*)d_out;

    char* p = (char*)d_ws;
    const size_t SZ_MAT = (size_t)MROWS * 256 * 4;          // 16.78 MB
    float* simq  = (float*)p;            p += (size_t)MROWS * NLM * 4;      // 2.62 MB
    float* simk  = (float*)p;            p += (size_t)MROWS * NLM * 4;      // 2.62 MB
    float* sel   = (float*)p;            p += (size_t)BATCH * NLM * 256 * 4;
    float* tmat  = (float*)p;            p += (size_t)BATCH * NLM * 256 * 4;
    float* qsum  = (float*)p;            p += (size_t)BATCH * 256 * 4;
    float* score = (float*)p;            p += (size_t)BATCH * SEQ * 4;
    float* q     = (float*)p;            p += SZ_MAT;
    float* k     = (float*)p;            p += SZ_MAT;
    float* v     = (float*)p;            p += SZ_MAT;
    float* outp  = q;   // alias: q is dead before out_pre_kernel runs

    hipMemsetAsync(qsum, 0, (size_t)BATCH * 256 * 4, stream);
    hipMemsetAsync(tmat, 0, (size_t)BATCH * NLM * 256 * 4, stream);

    const dim3 blk(256);
    const dim3 ggrid(4, MROWS / 128);
    gemm_nt<false><<<ggrid, blk, 0, stream>>>(query, Wq, bq, nullptr, q);
    gemm_nt<false><<<ggrid, blk, 0, stream>>>(query, Wk, bk, nullptr, k);
    gemm_nt<false><<<ggrid, blk, 0, stream>>>(query, Wv, bv, nullptr, v);

    qsum_kernel<<<dim3(SEQ / 256, BATCH), blk, 0, stream>>>(q, qsum);
    score_kernel<<<dim3(SEQ / 4, BATCH), blk, 0, stream>>>(k, qsum, score);
    topk_gather<<<dim3(BATCH), dim3(1024), 0, stream>>>(score, k, sel);

    sim_softmax_kernel<<<dim3(SEQ / 64, BATCH), blk, 0, stream>>>(q, sel, simq);
    sim_softmax_kernel<<<dim3(SEQ / 64, BATCH), blk, 0, stream>>>(k, sel, simk);
    tmat_kernel<<<dim3(SEQ / 128, 4, BATCH), blk, 0, stream>>>(simk, v, tmat);

    // out_pre writes outp (aliased onto q) — q is no longer read after simq
    out_pre_kernel<<<dim3(MROWS / 64), blk, 0, stream>>>(simq, tmat, outp);
    gemm_nt<true><<<ggrid, blk, 0, stream>>>(outp, Wo, bo, query, out);
}

// Round 5
// 312.154 us; speedup vs baseline: 3.0227x; 1.1560x over previous
//
#include <hip/hip_runtime.h>
#include <cstddef>
#include <cstdint>

// Problem constants (match reference)
#define BATCH 2
#define SEQ 8192
#define CH 256
#define NLM 40
#define MROWS (BATCH * SEQ)   // 16384
#define INV_SCALE 0.0625f     // 1/sqrt(256)

typedef unsigned short ushort_t;
typedef __attribute__((ext_vector_type(8))) short short8;    // 8 bf16 (4 VGPRs)
typedef __attribute__((ext_vector_type(4))) float floatx4;   // MFMA acc

// round-to-nearest-even fp32 -> bf16
__device__ __forceinline__ ushort_t f2bf(float f) {
    unsigned int u = __float_as_uint(f);
    u += 0x7FFFu + ((u >> 16) & 1u);
    return (ushort_t)(u >> 16);
}

// ---------------------------------------------------------------------------
// convert_x: fp32 [MROWS][256] -> bf16. grid 2048, block 256, 8 elems/thread.
// ---------------------------------------------------------------------------
__global__ __launch_bounds__(256) void convert_x(const float* __restrict__ x,
                                                 ushort_t* __restrict__ xbf) {
    const size_t i = ((size_t)blockIdx.x * 256 + threadIdx.x) * 8;
    const float4 a = *(const float4*)&x[i];
    const float4 c = *(const float4*)&x[i + 4];
    uint4 o;
    o.x = f2bf(a.x) | ((unsigned)f2bf(a.y) << 16);
    o.y = f2bf(a.z) | ((unsigned)f2bf(a.w) << 16);
    o.z = f2bf(c.x) | ((unsigned)f2bf(c.y) << 16);
    o.w = f2bf(c.z) | ((unsigned)f2bf(c.w) << 16);
    *(uint4*)&xbf[i] = o;
}

// ---------------------------------------------------------------------------
// convert_w: 4 weight matrices [256][256] fp32 -> bf16 (concat in wbf).
// grid (32, 4), block 256.
// ---------------------------------------------------------------------------
__global__ __launch_bounds__(256) void convert_w(const float* __restrict__ w0,
                                                 const float* __restrict__ w1,
                                                 const float* __restrict__ w2,
                                                 const float* __restrict__ w3,
                                                 ushort_t* __restrict__ wbf) {
    const float* src = (blockIdx.y == 0) ? w0 : (blockIdx.y == 1) ? w1
                     : (blockIdx.y == 2) ? w2 : w3;
    ushort_t* dst = wbf + (size_t)blockIdx.y * 65536;
    const size_t i = ((size_t)blockIdx.x * 256 + threadIdx.x) * 8;
    const float4 a = *(const float4*)&src[i];
    const float4 c = *(const float4*)&src[i + 4];
    uint4 o;
    o.x = f2bf(a.x) | ((unsigned)f2bf(a.y) << 16);
    o.y = f2bf(a.z) | ((unsigned)f2bf(a.w) << 16);
    o.z = f2bf(c.x) | ((unsigned)f2bf(c.y) << 16);
    o.w = f2bf(c.z) | ((unsigned)f2bf(c.w) << 16);
    *(uint4*)&dst[i] = o;
}

// ---------------------------------------------------------------------------
// MFMA GEMM NT: out[m][o] = sum_k A[m][k]*W[o][k] + bias[o] (+resid[m][o]).
// A,W bf16; out fp32. Tile 128x64, 256 thr (4 waves), mfma 16x16x32 bf16.
// Wave w: rows [w*32, w*32+32), acc[2][4] row-tiles x col-tiles.
// LDS row stride 40 bf16 (80 B = 5x16B): b128-aligned frag reads, 2-way bank
// aliasing only (free per m136). grid (4, 128).
// Fragment layouts (m89/m120-verified): A[m=lane&15][k=quad*8+j];
// B lane n=lane&15 holds W[o0+n][k=quad*8+j]; D col=lane&15,row=quad*4+reg.
// ---------------------------------------------------------------------------
template <bool RES>
__global__ __launch_bounds__(256) void gemm_bf16(const ushort_t* __restrict__ Abf,
                                                 const ushort_t* __restrict__ Wbf,
                                                 const float* __restrict__ bias,
                                                 const float* __restrict__ resid,
                                                 float* __restrict__ out) {
    __shared__ __align__(16) ushort_t As[128 * 40];
    __shared__ __align__(16) ushort_t Bs[64 * 40];
    const int t = threadIdx.x;
    const int o0 = blockIdx.x * 64;
    const int m0 = blockIdx.y * 128;
    const int lane = t & 63;
    const int w = t >> 6;
    const int quad = lane >> 4;
    const int l16 = lane & 15;

    floatx4 acc[2][4];
#pragma unroll
    for (int rt = 0; rt < 2; rt++)
#pragma unroll
        for (int ct = 0; ct < 4; ct++) acc[rt][ct] = (floatx4){0.f, 0.f, 0.f, 0.f};

    for (int kc = 0; kc < 256; kc += 32) {
        // Stage A tile: 128 rows x 32 k (bf16), 512 16B-chunks, 2/thread
#pragma unroll
        for (int u = 0; u < 2; u++) {
            const int cid = t + u * 256;
            const int row = cid >> 2, off = cid & 3;
            *(uint4*)&As[row * 40 + off * 8] =
                *(const uint4*)&Abf[(size_t)(m0 + row) * 256 + kc + off * 8];
        }
        // Stage W tile: 64 rows x 32 k
        {
            const int row = t >> 2, off = t & 3;
            *(uint4*)&Bs[row * 40 + off * 8] =
                *(const uint4*)&Wbf[(size_t)(o0 + row) * 256 + kc + off * 8];
        }
        __syncthreads();
        short8 a[2], b[4];
#pragma unroll
        for (int rt = 0; rt < 2; rt++)
            a[rt] = *(const short8*)&As[(w * 32 + rt * 16 + l16) * 40 + quad * 8];
#pragma unroll
        for (int ct = 0; ct < 4; ct++)
            b[ct] = *(const short8*)&Bs[(ct * 16 + l16) * 40 + quad * 8];
#pragma unroll
        for (int rt = 0; rt < 2; rt++)
#pragma unroll
            for (int ct = 0; ct < 4; ct++)
                acc[rt][ct] = __builtin_amdgcn_mfma_f32_16x16x32_bf16(
                    a[rt], b[ct], acc[rt][ct], 0, 0, 0);
        __syncthreads();
    }

    // Epilogue: D[row=quad*4+reg][col=l16] per 16x16 tile
#pragma unroll
    for (int rt = 0; rt < 2; rt++) {
#pragma unroll
        for (int ct = 0; ct < 4; ct++) {
            const int col = o0 + ct * 16 + l16;
            const float bb = bias[col];
#pragma unroll
            for (int reg = 0; reg < 4; reg++) {
                const int row = m0 + w * 32 + rt * 16 + quad * 4 + reg;
                float val = acc[rt][ct][reg] + bb;
                if (RES) val += resid[(size_t)row * 256 + col];
                out[(size_t)row * 256 + col] = val;
            }
        }
    }
}

// ---------------------------------------------------------------------------
// colsum: xsum[b][c] = sum_n x[b][n][c].  grid (64, B), block 256, pre-zeroed.
// ---------------------------------------------------------------------------
__global__ __launch_bounds__(256) void colsum_kernel(const float* __restrict__ x,
                                                     float* __restrict__ xsum) {
    const int b = blockIdx.y;
    const int r0 = blockIdx.x * 128;
    const int t = threadIdx.x;
    const float* base = x + ((size_t)b * SEQ + r0) * 256 + t;
    float s = 0.f;
    for (int i = 0; i < 128; i++) s += base[(size_t)i * 256];
    atomicAdd(&xsum[b * 256 + t], s);
}

// ---------------------------------------------------------------------------
// ws_kernel: ranking vector in fp32, independent of bf16 q/k.
//   qs = Wq @ xsum + N*bq   (N=8192 rows per batch)
//   ws[b] = Wk^T @ qs
// score_m = ws·x_m/16 + const  (const dropped — ranking-invariant).
// grid (B), block 256.
// ---------------------------------------------------------------------------
__global__ __launch_bounds__(256) void ws_kernel(const float* __restrict__ xsum,
                                                 const float* __restrict__ Wq,
                                                 const float* __restrict__ bq,
                                                 const float* __restrict__ Wk,
                                                 float* __restrict__ ws) {
    const int b = blockIdx.x;
    __shared__ float xs[256];
    __shared__ float qs[256];
    const int t = threadIdx.x;
    xs[t] = xsum[b * 256 + t];
    __syncthreads();
    const int lane = t & 63, w = t >> 6;
    // phase 1: wave w computes qs[o] for o = w*64 .. w*64+63 (full-wave dots)
    for (int g = 0; g < 64; g++) {
        const int o = w * 64 + g;
        const float4 wq = *(const float4*)&Wq[(size_t)o * 256 + lane * 4];
        const float4 x4 = *(const float4*)&xs[lane * 4];
        float d = wq.x * x4.x + wq.y * x4.y + wq.z * x4.z + wq.w * x4.w;
#pragma unroll
        for (int off = 32; off >= 1; off >>= 1) d += __shfl_down(d, off);
        if (lane == 0) qs[o] = d + 8192.0f * bq[o];
    }
    __syncthreads();
    // phase 2: ws[c=t] = sum_o Wk[o][c] * qs[o] (coalesced column reads)
    float a = 0.f;
    for (int o = 0; o < 256; o++) a += Wk[(size_t)o * 256 + t] * qs[o];
    ws[b * 256 + t] = a;
}

// ---------------------------------------------------------------------------
// score[b][m] = dot(x[b][m], ws[b]) / 16.  One wave per row. grid (SEQ/4, B).
// ---------------------------------------------------------------------------
__global__ __launch_bounds__(256) void score_kernel(const float* __restrict__ x,
                                                    const float* __restrict__ ws,
                                                    float* __restrict__ score) {
    const int b = blockIdx.y;
    const int m = blockIdx.x * 4 + (threadIdx.x >> 6);
    const int lane = threadIdx.x & 63;
    const float4 kv = *(const float4*)&x[((size_t)b * SEQ + m) * 256 + lane * 4];
    const float4 qs = *(const float4*)&ws[b * 256 + lane * 4];
    float d = kv.x * qs.x + kv.y * qs.y + kv.z * qs.z + kv.w * qs.w;
#pragma unroll
    for (int off = 32; off >= 1; off >>= 1) d += __shfl_down(d, off);
    if (lane == 0) score[(size_t)b * SEQ + m] = d * INV_SCALE;
}

// ---------------------------------------------------------------------------
// Top-40 + gather. grid (B), block 1024. Register-resident scores (8/thread);
// per round: 6-shuffle wave argmax, 16-entry LDS merge, 2 barriers; only the
// winner's owner rescans its 8 registers. (R4 version rescanned 8192-elem LDS
// every round: 60 us. Predicted ~8 us.)
// ---------------------------------------------------------------------------
__global__ __launch_bounds__(1024) void topk_gather(const float* __restrict__ score,
                                                    const float* __restrict__ kmat,
                                                    float* __restrict__ sel) {
    const int b = blockIdx.x;
    __shared__ float wv[16];
    __shared__ int   wi[16];
    __shared__ int   top[NLM];
    __shared__ int   bwin_s;
    const int t = threadIdx.x;

    float v[8];
#pragma unroll
    for (int j = 0; j < 8; j++) v[j] = score[(size_t)b * SEQ + t + j * 1024];

    float lmax = v[0];
    int lidx = t;
#pragma unroll
    for (int j = 1; j < 8; j++)
        if (v[j] > lmax) { lmax = v[j]; lidx = t + j * 1024; }

    for (int it = 0; it < NLM; it++) {
        float best = lmax;
        int bi = lidx;
#pragma unroll
        for (int off = 32; off >= 1; off >>= 1) {
            const float ov = __shfl_down(best, off);
            const int   oi = __shfl_down(bi, off);
            if (ov > best || (ov == best && oi < bi)) { best = ov; bi = oi; }
        }
        if ((t & 63) == 0) { wv[t >> 6] = best; wi[t >> 6] = bi; }
        __syncthreads();
        if (t < 64) {
            best = (t < 16) ? wv[t] : -3.0e38f;
            bi   = (t < 16) ? wi[t] : 0x7fffffff;
#pragma unroll
            for (int off = 8; off >= 1; off >>= 1) {
                const float ov = __shfl_down(best, off);
                const int   oi = __shfl_down(bi, off);
                if (ov > best || (ov == best && oi < bi)) { best = ov; bi = oi; }
            }
            if (t == 0) { top[it] = bi; bwin_s = bi; }
        }
        __syncthreads();
        const int bw = bwin_s;
        if ((bw & 1023) == t) {
            const int slot = bw >> 10;
#pragma unroll
            for (int j = 0; j < 8; j++)
                if (j == slot) v[j] = -3.0e38f;
            lmax = v[0]; lidx = t;
#pragma unroll
            for (int j = 1; j < 8; j++)
                if (v[j] > lmax) { lmax = v[j]; lidx = t + j * 1024; }
        }
    }
    __syncthreads();
    // Gather selected keys: sel[b][j][c] = k[b][top[j]][c]
    for (int f = t; f < NLM * 256; f += 1024) {
        const int j = f >> 8;
        const int c = f & 255;
        sel[(size_t)b * NLM * 256 + f] = kmat[((size_t)b * SEQ + top[j]) * 256 + c];
    }
}

// ---------------------------------------------------------------------------
// sim softmax: sim[b][n][lm] = softmax_lm(A[b][n]·sel[b][lm] / 16).
// grid (SEQ/64, B), block 256. Thread t: row r = t>>2, landmark group c = t&3
// covering lm = c*10 .. c*10+9. Bounded unroll (R3 spill lesson).
// ---------------------------------------------------------------------------
__global__ __launch_bounds__(256, 4) void sim_softmax_kernel(const float* __restrict__ A,
                                                             const float* __restrict__ sel,
                                                             float* __restrict__ sim) {
    __shared__ float As_[64][68];
    __shared__ float St_[40][68];
    const int b = blockIdx.y;
    const int n0 = blockIdx.x * 64;
    const int t = threadIdx.x;
    const int r = t >> 2, c = t & 3;
    const float* __restrict__ Arow = A + ((size_t)b * SEQ + n0) * 256;
    const float* __restrict__ Sb = sel + (size_t)b * NLM * 256;

    float acc[10];
#pragma unroll
    for (int j = 0; j < 10; j++) acc[j] = 0.f;

    for (int kc = 0; kc < 256; kc += 64) {
#pragma unroll
        for (int u = 0; u < 4; u++) {
            const int f = t + u * 256;
            const int row = f >> 4;
            const int c4 = (f & 15) * 4;
            *(float4*)&As_[row][c4] = *(const float4*)&Arow[(size_t)row * 256 + kc + c4];
        }
#pragma unroll
        for (int u = 0; u < 3; u++) {
            const int f = t + u * 256;
            if (f < 640) {
                const int row = f >> 4;
                const int c4 = (f & 15) * 4;
                *(float4*)&St_[row][c4] = *(const float4*)&Sb[(size_t)row * 256 + kc + c4];
            }
        }
        __syncthreads();
#pragma unroll 1
        for (int i = 0; i < 64; i += 4) {
            const float4 a = *(const float4*)&As_[r][i];
#pragma unroll
            for (int j = 0; j < 10; j++) {
                const float4 s = *(const float4*)&St_[c * 10 + j][i];
                acc[j] = fmaf(a.x, s.x, acc[j]);
                acc[j] = fmaf(a.y, s.y, acc[j]);
                acc[j] = fmaf(a.z, s.z, acc[j]);
                acc[j] = fmaf(a.w, s.w, acc[j]);
            }
        }
        __syncthreads();
    }

    float mx = -1e30f;
#pragma unroll
    for (int j = 0; j < 10; j++) {
        acc[j] *= INV_SCALE;
        mx = fmaxf(mx, acc[j]);
    }
    mx = fmaxf(mx, __shfl_xor(mx, 1));
    mx = fmaxf(mx, __shfl_xor(mx, 2));
    float sum = 0.f;
#pragma unroll
    for (int j = 0; j < 10; j++) {
        acc[j] = expf(acc[j] - mx);
        sum += acc[j];
    }
    sum += __shfl_xor(sum, 1);
    sum += __shfl_xor(sum, 2);
    const float inv = 1.f / sum;
#pragma unroll
    for (int j = 0; j < 10; j++) acc[j] *= inv;

    float* __restrict__ dst = &sim[((size_t)b * SEQ + n0 + r) * NLM + c * 10];
#pragma unroll
    for (int j2 = 0; j2 < 5; j2++) {
        float2 o; o.x = acc[2 * j2]; o.y = acc[2 * j2 + 1];
        *(float2*)&dst[2 * j2] = o;
    }
}

// ---------------------------------------------------------------------------
// tmat_kernel: t[b][l][cc] = sum_m simk[b][m][l] * v[b][m][cc]
// grid (SEQ/128, 4, B); tmat pre-zeroed, atomicAdd partials.
// ---------------------------------------------------------------------------
__global__ __launch_bounds__(256) void tmat_kernel(const float* __restrict__ simk,
                                                   const float* __restrict__ v,
                                                   float* __restrict__ tmat) {
    __shared__ float Ps[128][12];
    const int b  = blockIdx.z;
    const int lg = blockIdx.y;
    const int n0 = blockIdx.x * 128;
    const int t  = threadIdx.x;

    for (int f = t; f < 128 * 10; f += 256) {
        const int row = f / 10;
        const int l   = f - row * 10;
        Ps[row][l] = simk[((size_t)b * SEQ + n0 + row) * NLM + lg * 10 + l];
    }
    __syncthreads();

    float tac[10];
#pragma unroll
    for (int j = 0; j < 10; j++) tac[j] = 0.f;

    const float* Vb = v + ((size_t)b * SEQ + n0) * 256 + t;
#pragma unroll 4
    for (int m = 0; m < 128; m++) {
        const float vv = Vb[(size_t)m * 256];
        const float4 p0 = *(const float4*)&Ps[m][0];
        const float4 p1 = *(const float4*)&Ps[m][4];
        const float2 p2 = *(const float2*)&Ps[m][8];
        tac[0] = fmaf(p0.x, vv, tac[0]);
        tac[1] = fmaf(p0.y, vv, tac[1]);
        tac[2] = fmaf(p0.z, vv, tac[2]);
        tac[3] = fmaf(p0.w, vv, tac[3]);
        tac[4] = fmaf(p1.x, vv, tac[4]);
        tac[5] = fmaf(p1.y, vv, tac[5]);
        tac[6] = fmaf(p1.z, vv, tac[6]);
        tac[7] = fmaf(p1.w, vv, tac[7]);
        tac[8] = fmaf(p2.x, vv, tac[8]);
        tac[9] = fmaf(p2.y, vv, tac[9]);
    }
#pragma unroll
    for (int j = 0; j < 10; j++)
        atomicAdd(&tmat[(size_t)b * NLM * 256 + (lg * 10 + j) * 256 + t], tac[j]);
}

// ---------------------------------------------------------------------------
// out_pre[g][cc] = sum_l simq[g][l] * t[b][l][cc] -> bf16 (feeds final GEMM).
// grid (MROWS/64), block 256.
// ---------------------------------------------------------------------------
__global__ __launch_bounds__(256) void out_pre_kernel(const float* __restrict__ simq,
                                                      const float* __restrict__ tmat,
                                                      ushort_t* __restrict__ outp_bf) {
    __shared__ float Pm[64][40];
    const int g0 = blockIdx.x * 64;
    const int b = g0 >> 13;
    const int t = threadIdx.x;
    float* pflat = &Pm[0][0];
    for (int f = t; f < 64 * NLM; f += 256) pflat[f] = simq[(size_t)g0 * NLM + f];
    float tc[40];
#pragma unroll
    for (int l = 0; l < 40; l++) tc[l] = tmat[(size_t)b * NLM * 256 + l * 256 + t];
    __syncthreads();
#pragma unroll 2
    for (int m = 0; m < 64; m++) {
        float a = 0.f;
#pragma unroll
        for (int j4 = 0; j4 < 10; j4++) {
            const float4 p = *(const float4*)&Pm[m][j4 * 4];
            a = fmaf(p.x, tc[j4 * 4 + 0], a);
            a = fmaf(p.y, tc[j4 * 4 + 1], a);
            a = fmaf(p.z, tc[j4 * 4 + 2], a);
            a = fmaf(p.w, tc[j4 * 4 + 3], a);
        }
        outp_bf[((size_t)g0 + m) * 256 + t] = f2bf(a);
    }
}

// ---------------------------------------------------------------------------
// Workspace (~64.7 MB total; R1 proved ~70 MB safe, R2 failed at ~72.6):
//   smalls first, then fp32 mats, then bf16 buffers.
//   outp_bf ALIASES xbf (xbf dead after gemm_v; out_pre runs later).
// ---------------------------------------------------------------------------
extern "C" void kernel_launch(void* const* d_in, const int* in_sizes, int n_in,
                              void* d_out, int out_size, void* d_ws, size_t ws_size,
                              hipStream_t stream) {
    const float* query = (const float*)d_in[0];
    const float* Wq = (const float*)d_in[1];
    const float* bq = (const float*)d_in[2];
    const float* Wk = (const float*)d_in[3];
    const float* bk = (const float*)d_in[4];
    const float* Wv = (const float*)d_in[5];
    const float* bv = (const float*)d_in[6];
    const float* Wo = (const float*)d_in[7];
    const float* bo = (const float*)d_in[8];
    float* out = (float*)d_out;
    (void)bk;

    char* p = (char*)d_ws;
    const size_t SZ_MAT = (size_t)MROWS * 256 * 4;          // 16.78 MB
    float* simq  = (float*)p;            p += (size_t)MROWS * NLM * 4;      // 2.62 MB
    float* simk  = (float*)p;            p += (size_t)MROWS * NLM * 4;      // 2.62 MB
    float* sel   = (float*)p;            p += (size_t)BATCH * NLM * 256 * 4;
    float* tmat  = (float*)p;            p += (size_t)BATCH * NLM * 256 * 4;
    float* xsum  = (float*)p;            p += (size_t)BATCH * 256 * 4;
    float* ws    = (float*)p;            p += (size_t)BATCH * 256 * 4;
    float* score = (float*)p;            p += (size_t)BATCH * SEQ * 4;
    float* q     = (float*)p;            p += SZ_MAT;
    float* k     = (float*)p;            p += SZ_MAT;
    float* v     = (float*)p;            p += SZ_MAT;
    ushort_t* xbf = (ushort_t*)p;        p += (size_t)MROWS * 256 * 2;      // 8.39 MB
    ushort_t* wbf = (ushort_t*)p;        p += (size_t)4 * 256 * 256 * 2;    // 512 KB
    ushort_t* outp_bf = xbf;  // alias: xbf dead after gemm_v

    hipMemsetAsync(xsum, 0, (size_t)BATCH * 256 * 4, stream);
    hipMemsetAsync(tmat, 0, (size_t)BATCH * NLM * 256 * 4, stream);

    const dim3 blk(256);
    const dim3 ggrid(4, MROWS / 128);

    convert_x<<<dim3(MROWS * 256 / 2048), blk, 0, stream>>>(query, xbf);
    convert_w<<<dim3(32, 4), blk, 0, stream>>>(Wq, Wk, Wv, Wo, wbf);
    colsum_kernel<<<dim3(64, BATCH), blk, 0, stream>>>(query, xsum);
    ws_kernel<<<dim3(BATCH), blk, 0, stream>>>(xsum, Wq, bq, Wk, ws);
    score_kernel<<<dim3(SEQ / 4, BATCH), blk, 0, stream>>>(query, ws, score);

    gemm_bf16<false><<<ggrid, blk, 0, stream>>>(xbf, wbf,           bq, nullptr, q);
    gemm_bf16<false><<<ggrid, blk, 0, stream>>>(xbf, wbf + 65536,   bk, nullptr, k);
    gemm_bf16<false><<<ggrid, blk, 0, stream>>>(xbf, wbf + 131072,  bv, nullptr, v);

    topk_gather<<<dim3(BATCH), dim3(1024), 0, stream>>>(score, k, sel);

    sim_softmax_kernel<<<dim3(SEQ / 64, BATCH), blk, 0, stream>>>(q, sel, simq);
    sim_softmax_kernel<<<dim3(SEQ / 64, BATCH), blk, 0, stream>>>(k, sel, simk);
    tmat_kernel<<<dim3(SEQ / 128, 4, BATCH), blk, 0, stream>>>(simk, v, tmat);

    out_pre_kernel<<<dim3(MROWS / 64), blk, 0, stream>>>(simq, tmat, outp_bf);
    gemm_bf16<true><<<ggrid, blk, 0, stream>>>(outp_bf, wbf + 196608, bo, query, out);
}

// Round 6
// 267.495 us; speedup vs baseline: 3.5273x; 1.1670x over previous
//
#include <hip/hip_runtime.h>
#include <cstddef>
#include <cstdint>

// Problem constants (match reference)
#define BATCH 2
#define SEQ 8192
#define CH 256
#define NLM 40
#define MROWS (BATCH * SEQ)   // 16384
#define INV_SCALE 0.0625f     // 1/sqrt(256)

typedef unsigned short ushort_t;
typedef __attribute__((ext_vector_type(8))) short short8;    // 8 bf16 (4 VGPRs)
typedef __attribute__((ext_vector_type(4))) float floatx4;   // MFMA acc

// round-to-nearest-even fp32 -> bf16
__device__ __forceinline__ ushort_t f2bf(float f) {
    unsigned int u = __float_as_uint(f);
    u += 0x7FFFu + ((u >> 16) & 1u);
    return (ushort_t)(u >> 16);
}

// ---------------------------------------------------------------------------
// convert_x: fp32 [MROWS][256] -> bf16. grid 2048, block 256, 8 elems/thread.
// ---------------------------------------------------------------------------
__global__ __launch_bounds__(256) void convert_x(const float* __restrict__ x,
                                                 ushort_t* __restrict__ xbf) {
    const size_t i = ((size_t)blockIdx.x * 256 + threadIdx.x) * 8;
    const float4 a = *(const float4*)&x[i];
    const float4 c = *(const float4*)&x[i + 4];
    uint4 o;
    o.x = f2bf(a.x) | ((unsigned)f2bf(a.y) << 16);
    o.y = f2bf(a.z) | ((unsigned)f2bf(a.w) << 16);
    o.z = f2bf(c.x) | ((unsigned)f2bf(c.y) << 16);
    o.w = f2bf(c.z) | ((unsigned)f2bf(c.w) << 16);
    *(uint4*)&xbf[i] = o;
}

// ---------------------------------------------------------------------------
// convert_w: 4 weight matrices [256][256] fp32 -> bf16 (concat in wbf).
// grid (32, 4), block 256.
// ---------------------------------------------------------------------------
__global__ __launch_bounds__(256) void convert_w(const float* __restrict__ w0,
                                                 const float* __restrict__ w1,
                                                 const float* __restrict__ w2,
                                                 const float* __restrict__ w3,
                                                 ushort_t* __restrict__ wbf) {
    const float* src = (blockIdx.y == 0) ? w0 : (blockIdx.y == 1) ? w1
                     : (blockIdx.y == 2) ? w2 : w3;
    ushort_t* dst = wbf + (size_t)blockIdx.y * 65536;
    const size_t i = ((size_t)blockIdx.x * 256 + threadIdx.x) * 8;
    const float4 a = *(const float4*)&src[i];
    const float4 c = *(const float4*)&src[i + 4];
    uint4 o;
    o.x = f2bf(a.x) | ((unsigned)f2bf(a.y) << 16);
    o.y = f2bf(a.z) | ((unsigned)f2bf(a.w) << 16);
    o.z = f2bf(c.x) | ((unsigned)f2bf(c.y) << 16);
    o.w = f2bf(c.z) | ((unsigned)f2bf(c.w) << 16);
    *(uint4*)&dst[i] = o;
}

// ---------------------------------------------------------------------------
// MFMA GEMM NT: out[m][o] = sum_k A[m][k]*W[o][k] + bias[o] (+resid[m][o]).
// A,W bf16; out fp32. Tile 128x64, 256 thr (4 waves), mfma 16x16x32 bf16.
// LDS row stride 40 bf16 (80 B = 5x16B): b128-aligned frag reads, 2-way bank
// aliasing only (free per m136). grid (4, 128).
// Fragment layouts (m89/m120-verified): A[m=lane&15][k=quad*8+j];
// B lane n=lane&15 holds W[o0+n][k=quad*8+j]; D col=lane&15,row=quad*4+reg.
// ---------------------------------------------------------------------------
template <bool RES>
__global__ __launch_bounds__(256) void gemm_bf16(const ushort_t* __restrict__ Abf,
                                                 const ushort_t* __restrict__ Wbf,
                                                 const float* __restrict__ bias,
                                                 const float* __restrict__ resid,
                                                 float* __restrict__ out) {
    __shared__ __align__(16) ushort_t As[128 * 40];
    __shared__ __align__(16) ushort_t Bs[64 * 40];
    const int t = threadIdx.x;
    const int o0 = blockIdx.x * 64;
    const int m0 = blockIdx.y * 128;
    const int lane = t & 63;
    const int w = t >> 6;
    const int quad = lane >> 4;
    const int l16 = lane & 15;

    floatx4 acc[2][4];
#pragma unroll
    for (int rt = 0; rt < 2; rt++)
#pragma unroll
        for (int ct = 0; ct < 4; ct++) acc[rt][ct] = (floatx4){0.f, 0.f, 0.f, 0.f};

    for (int kc = 0; kc < 256; kc += 32) {
        // Stage A tile: 128 rows x 32 k (bf16), 512 16B-chunks, 2/thread
#pragma unroll
        for (int u = 0; u < 2; u++) {
            const int cid = t + u * 256;
            const int row = cid >> 2, off = cid & 3;
            *(uint4*)&As[row * 40 + off * 8] =
                *(const uint4*)&Abf[(size_t)(m0 + row) * 256 + kc + off * 8];
        }
        // Stage W tile: 64 rows x 32 k
        {
            const int row = t >> 2, off = t & 3;
            *(uint4*)&Bs[row * 40 + off * 8] =
                *(const uint4*)&Wbf[(size_t)(o0 + row) * 256 + kc + off * 8];
        }
        __syncthreads();
        short8 a[2], b[4];
#pragma unroll
        for (int rt = 0; rt < 2; rt++)
            a[rt] = *(const short8*)&As[(w * 32 + rt * 16 + l16) * 40 + quad * 8];
#pragma unroll
        for (int ct = 0; ct < 4; ct++)
            b[ct] = *(const short8*)&Bs[(ct * 16 + l16) * 40 + quad * 8];
#pragma unroll
        for (int rt = 0; rt < 2; rt++)
#pragma unroll
            for (int ct = 0; ct < 4; ct++)
                acc[rt][ct] = __builtin_amdgcn_mfma_f32_16x16x32_bf16(
                    a[rt], b[ct], acc[rt][ct], 0, 0, 0);
        __syncthreads();
    }

    // Epilogue: D[row=quad*4+reg][col=l16] per 16x16 tile
#pragma unroll
    for (int rt = 0; rt < 2; rt++) {
#pragma unroll
        for (int ct = 0; ct < 4; ct++) {
            const int col = o0 + ct * 16 + l16;
            const float bb = bias[col];
#pragma unroll
            for (int reg = 0; reg < 4; reg++) {
                const int row = m0 + w * 32 + rt * 16 + quad * 4 + reg;
                float val = acc[rt][ct][reg] + bb;
                if (RES) val += resid[(size_t)row * 256 + col];
                out[(size_t)row * 256 + col] = val;
            }
        }
    }
}

// ---------------------------------------------------------------------------
// colsum: xsum[b][c] = sum_n x[b][n][c].  grid (64, B), block 256, pre-zeroed.
// ---------------------------------------------------------------------------
__global__ __launch_bounds__(256) void colsum_kernel(const float* __restrict__ x,
                                                     float* __restrict__ xsum) {
    const int b = blockIdx.y;
    const int r0 = blockIdx.x * 128;
    const int t = threadIdx.x;
    const float* base = x + ((size_t)b * SEQ + r0) * 256 + t;
    float s = 0.f;
    for (int i = 0; i < 128; i++) s += base[(size_t)i * 256];
    atomicAdd(&xsum[b * 256 + t], s);
}

// ---------------------------------------------------------------------------
// ws_kernel: ranking vector in fp32, independent of bf16 q/k.
//   qs = Wq @ xsum + N*bq ;  ws[b] = Wk^T @ qs
// score_m = ws·x_m/16 + const  (const dropped — ranking-invariant).
// grid (B), block 1024 (R5's 256-thread version serialized 64 wave-dots per
// wave in phase 1 ≈ 10K cyc; 16 waves now do 16 each).
// ---------------------------------------------------------------------------
__global__ __launch_bounds__(1024) void ws_kernel(const float* __restrict__ xsum,
                                                  const float* __restrict__ Wq,
                                                  const float* __restrict__ bq,
                                                  const float* __restrict__ Wk,
                                                  float* __restrict__ ws) {
    const int b = blockIdx.x;
    __shared__ float xs[256];
    __shared__ float qs[256];
    __shared__ float ppart[4][256];
    const int t = threadIdx.x;
    if (t < 256) xs[t] = xsum[b * 256 + t];
    __syncthreads();
    const int lane = t & 63, w = t >> 6;
    // phase 1: wave w computes qs[o] for o = w*16 .. w*16+15
    for (int g = 0; g < 16; g++) {
        const int o = w * 16 + g;
        const float4 wq = *(const float4*)&Wq[(size_t)o * 256 + lane * 4];
        const float4 x4 = *(const float4*)&xs[lane * 4];
        float d = wq.x * x4.x + wq.y * x4.y + wq.z * x4.z + wq.w * x4.w;
#pragma unroll
        for (int off = 32; off >= 1; off >>= 1) d += __shfl_down(d, off);
        if (lane == 0) qs[o] = d + 8192.0f * bq[o];
    }
    __syncthreads();
    // phase 2: split-K over 4 groups; ws[c] = sum_o Wk[o][c] * qs[o]
    const int c = t & 255, part = t >> 8;
    float a = 0.f;
    for (int o = part * 64; o < part * 64 + 64; o++)
        a += Wk[(size_t)o * 256 + c] * qs[o];
    ppart[part][c] = a;
    __syncthreads();
    if (t < 256)
        ws[b * 256 + t] = ppart[0][t] + ppart[1][t] + ppart[2][t] + ppart[3][t];
}

// ---------------------------------------------------------------------------
// score[b][m] = dot(x[b][m], ws[b]) / 16.  One wave per row. grid (SEQ/4, B).
// ---------------------------------------------------------------------------
__global__ __launch_bounds__(256) void score_kernel(const float* __restrict__ x,
                                                    const float* __restrict__ ws,
                                                    float* __restrict__ score) {
    const int b = blockIdx.y;
    const int m = blockIdx.x * 4 + (threadIdx.x >> 6);
    const int lane = threadIdx.x & 63;
    const float4 kv = *(const float4*)&x[((size_t)b * SEQ + m) * 256 + lane * 4];
    const float4 qs = *(const float4*)&ws[b * 256 + lane * 4];
    float d = kv.x * qs.x + kv.y * qs.y + kv.z * qs.z + kv.w * qs.w;
#pragma unroll
    for (int off = 32; off >= 1; off >>= 1) d += __shfl_down(d, off);
    if (lane == 0) score[(size_t)b * SEQ + m] = d * INV_SCALE;
}

// ---------------------------------------------------------------------------
// Top-40 + gather via RADIX-SELECT. grid (B), block 1024.
// R5's iterative argmax was latency-bound at 3.4K cyc/round x 40 rounds
// (56 us). Radix: 4 levels of 256-bin LDS histogram on sortable keys ->
// exact 40th key; one compaction pass; 64-lane bitonic sort for
// deterministic slot order. ~10 barriers total, no serial 40-round chain.
// ---------------------------------------------------------------------------
__global__ __launch_bounds__(1024) void topk_gather(const float* __restrict__ score,
                                                    const float* __restrict__ kmat,
                                                    float* __restrict__ sel) {
    const int b = blockIdx.x;
    const int t = threadIdx.x;
    __shared__ unsigned hist[256];
    __shared__ unsigned wsum[64];
    __shared__ unsigned sPrefix, sMask, sRem, sNeq;
    __shared__ int sNgt;
    __shared__ int top[NLM];
    __shared__ unsigned topkey[NLM];

    // sortable keys: monotone u32 (flip sign bit for +, all bits for -)
    unsigned key[8];
#pragma unroll
    for (int j = 0; j < 8; j++) {
        const unsigned u = __float_as_uint(score[(size_t)b * SEQ + t + j * 1024]);
        key[j] = u ^ (unsigned)(((int)u >> 31) | 0x80000000);
    }
    if (t == 0) { sPrefix = 0; sMask = 0; sRem = NLM; sNgt = 0; sNeq = 0; }

    for (int lvl = 0; lvl < 4; lvl++) {
        const int shift = 24 - 8 * lvl;
        if (t < 256) hist[t] = 0;
        __syncthreads();
        const unsigned pfx = sPrefix, msk = sMask;
#pragma unroll
        for (int j = 0; j < 8; j++)
            if (((key[j] ^ pfx) & msk) == 0)
                atomicAdd(&hist[(key[j] >> shift) & 255u], 1u);
        __syncthreads();
        if (t < 64) wsum[t] = hist[t * 4] + hist[t * 4 + 1] + hist[t * 4 + 2] + hist[t * 4 + 3];
        __syncthreads();
        if (t == 0) {
            // descend from the top: find digit d where cumulative count >= rem
            unsigned rem = sRem, cum = 0;
            int g = 63;
            for (; g > 0; g--) { if (cum + wsum[g] >= rem) break; cum += wsum[g]; }
            int d = g * 4 + 3;
            for (; d > g * 4; d--) { if (cum + hist[d] >= rem) break; cum += hist[d]; }
            sRem = rem - cum;
            sPrefix |= ((unsigned)d) << shift;
            sMask |= 255u << shift;
        }
        __syncthreads();
    }
    const unsigned K40 = sPrefix;       // exact key of the 40th largest
    const unsigned rem = sRem;          // how many ==K40 to take
    const int ngt = NLM - (int)rem;     // count of keys strictly greater

    // compact: slots [0,ngt) for >K40 (atomic order), [ngt,40) for ==K40
#pragma unroll
    for (int j = 0; j < 8; j++) {
        if (key[j] > K40) {
            const int slot = atomicAdd(&sNgt, 1);
            top[slot] = t + j * 1024; topkey[slot] = key[j];
        } else if (key[j] == K40) {
            const unsigned e = atomicAdd(&sNeq, 1u);
            if (e < rem) {
                const int slot = ngt + (int)e;
                top[slot] = t + j * 1024; topkey[slot] = key[j];
            }
        }
    }
    __syncthreads();

    // deterministic slot order: wave-0 bitonic sort, desc key / asc idx
    if (t < 64) {
        unsigned long long c = (t < NLM)
            ? ((((unsigned long long)(~topkey[t])) << 32) | (unsigned)top[t])
            : 0xFFFFFFFFFFFFFFFFull;
#pragma unroll
        for (int kk = 2; kk <= 64; kk <<= 1) {
#pragma unroll
            for (int j = kk >> 1; j >= 1; j >>= 1) {
                const unsigned long long o = __shfl_xor(c, j);
                const bool takeMin = ((t & kk) == 0) == ((t & j) == 0);
                const bool less = c < o;
                c = (takeMin == less) ? c : o;
            }
        }
        if (t < NLM) top[t] = (int)(c & 0xFFFFFFFFu);
    }
    __syncthreads();

    // gather selected keys: sel[b][j][cc] = k[b][top[j]][cc]
    for (int f = t; f < NLM * 256; f += 1024) {
        const int j = f >> 8;
        const int cc = f & 255;
        sel[(size_t)b * NLM * 256 + f] = kmat[((size_t)b * SEQ + top[j]) * 256 + cc];
    }
}

// ---------------------------------------------------------------------------
// sim softmax: sim[b][n][lm] = softmax_lm(A[b][n]·sel[b][lm] / 16).
// grid (SEQ/64, B), block 256. Thread t: row r = t>>2, landmark group c = t&3
// covering lm = c*10 .. c*10+9. Bounded unroll (R3 spill lesson).
// ---------------------------------------------------------------------------
__global__ __launch_bounds__(256, 4) void sim_softmax_kernel(const float* __restrict__ A,
                                                             const float* __restrict__ sel,
                                                             float* __restrict__ sim) {
    __shared__ float As_[64][68];
    __shared__ float St_[40][68];
    const int b = blockIdx.y;
    const int n0 = blockIdx.x * 64;
    const int t = threadIdx.x;
    const int r = t >> 2, c = t & 3;
    const float* __restrict__ Arow = A + ((size_t)b * SEQ + n0) * 256;
    const float* __restrict__ Sb = sel + (size_t)b * NLM * 256;

    float acc[10];
#pragma unroll
    for (int j = 0; j < 10; j++) acc[j] = 0.f;

    for (int kc = 0; kc < 256; kc += 64) {
#pragma unroll
        for (int u = 0; u < 4; u++) {
            const int f = t + u * 256;
            const int row = f >> 4;
            const int c4 = (f & 15) * 4;
            *(float4*)&As_[row][c4] = *(const float4*)&Arow[(size_t)row * 256 + kc + c4];
        }
#pragma unroll
        for (int u = 0; u < 3; u++) {
            const int f = t + u * 256;
            if (f < 640) {
                const int row = f >> 4;
                const int c4 = (f & 15) * 4;
                *(float4*)&St_[row][c4] = *(const float4*)&Sb[(size_t)row * 256 + kc + c4];
            }
        }
        __syncthreads();
#pragma unroll 1
        for (int i = 0; i < 64; i += 4) {
            const float4 a = *(const float4*)&As_[r][i];
#pragma unroll
            for (int j = 0; j < 10; j++) {
                const float4 s = *(const float4*)&St_[c * 10 + j][i];
                acc[j] = fmaf(a.x, s.x, acc[j]);
                acc[j] = fmaf(a.y, s.y, acc[j]);
                acc[j] = fmaf(a.z, s.z, acc[j]);
                acc[j] = fmaf(a.w, s.w, acc[j]);
            }
        }
        __syncthreads();
    }

    float mx = -1e30f;
#pragma unroll
    for (int j = 0; j < 10; j++) {
        acc[j] *= INV_SCALE;
        mx = fmaxf(mx, acc[j]);
    }
    mx = fmaxf(mx, __shfl_xor(mx, 1));
    mx = fmaxf(mx, __shfl_xor(mx, 2));
    float sum = 0.f;
#pragma unroll
    for (int j = 0; j < 10; j++) {
        acc[j] = expf(acc[j] - mx);
        sum += acc[j];
    }
    sum += __shfl_xor(sum, 1);
    sum += __shfl_xor(sum, 2);
    const float inv = 1.f / sum;
#pragma unroll
    for (int j = 0; j < 10; j++) acc[j] *= inv;

    float* __restrict__ dst = &sim[((size_t)b * SEQ + n0 + r) * NLM + c * 10];
#pragma unroll
    for (int j2 = 0; j2 < 5; j2++) {
        float2 o; o.x = acc[2 * j2]; o.y = acc[2 * j2 + 1];
        *(float2*)&dst[2 * j2] = o;
    }
}

// ---------------------------------------------------------------------------
// tmat_kernel: t[b][l][cc] = sum_m simk[b][m][l] * v[b][m][cc]
// grid (SEQ/128, 2, B): 20 landmarks per group (was 4 groups of 10 -> v was
// fetched 4x; now 2x). tac[20] ~60 live VGPRs, unroll 2 — no spill.
// tmat pre-zeroed, atomicAdd partials.
// ---------------------------------------------------------------------------
__global__ __launch_bounds__(256) void tmat_kernel(const float* __restrict__ simk,
                                                   const float* __restrict__ v,
                                                   float* __restrict__ tmat) {
    __shared__ float Ps[128][20];   // rows 80 B: &Ps[m][4j] stays 16B-aligned
    const int b  = blockIdx.z;
    const int lg = blockIdx.y;      // landmark group: lm = lg*20 .. lg*20+19
    const int n0 = blockIdx.x * 128;
    const int t  = threadIdx.x;

    for (int f = t; f < 128 * 20; f += 256) {
        const int row = f / 20;
        const int l   = f - row * 20;
        Ps[row][l] = simk[((size_t)b * SEQ + n0 + row) * NLM + lg * 20 + l];
    }
    __syncthreads();

    float tac[20];
#pragma unroll
    for (int j = 0; j < 20; j++) tac[j] = 0.f;

    const float* Vb = v + ((size_t)b * SEQ + n0) * 256 + t;
#pragma unroll 2
    for (int m = 0; m < 128; m++) {
        const float vv = Vb[(size_t)m * 256];
#pragma unroll
        for (int j4 = 0; j4 < 5; j4++) {
            const float4 p = *(const float4*)&Ps[m][j4 * 4];  // broadcast reads
            tac[j4 * 4 + 0] = fmaf(p.x, vv, tac[j4 * 4 + 0]);
            tac[j4 * 4 + 1] = fmaf(p.y, vv, tac[j4 * 4 + 1]);
            tac[j4 * 4 + 2] = fmaf(p.z, vv, tac[j4 * 4 + 2]);
            tac[j4 * 4 + 3] = fmaf(p.w, vv, tac[j4 * 4 + 3]);
        }
    }
#pragma unroll
    for (int j = 0; j < 20; j++)
        atomicAdd(&tmat[(size_t)b * NLM * 256 + (lg * 20 + j) * 256 + t], tac[j]);
}

// ---------------------------------------------------------------------------
// out_pre[g][cc] = sum_l simq[g][l] * t[b][l][cc] -> bf16 (feeds final GEMM).
// grid (MROWS/64), block 256.
// ---------------------------------------------------------------------------
__global__ __launch_bounds__(256) void out_pre_kernel(const float* __restrict__ simq,
                                                      const float* __restrict__ tmat,
                                                      ushort_t* __restrict__ outp_bf) {
    __shared__ float Pm[64][40];
    const int g0 = blockIdx.x * 64;
    const int b = g0 >> 13;
    const int t = threadIdx.x;
    float* pflat = &Pm[0][0];
    for (int f = t; f < 64 * NLM; f += 256) pflat[f] = simq[(size_t)g0 * NLM + f];
    float tc[40];
#pragma unroll
    for (int l = 0; l < 40; l++) tc[l] = tmat[(size_t)b * NLM * 256 + l * 256 + t];
    __syncthreads();
#pragma unroll 2
    for (int m = 0; m < 64; m++) {
        float a = 0.f;
#pragma unroll
        for (int j4 = 0; j4 < 10; j4++) {
            const float4 p = *(const float4*)&Pm[m][j4 * 4];
            a = fmaf(p.x, tc[j4 * 4 + 0], a);
            a = fmaf(p.y, tc[j4 * 4 + 1], a);
            a = fmaf(p.z, tc[j4 * 4 + 2], a);
            a = fmaf(p.w, tc[j4 * 4 + 3], a);
        }
        outp_bf[((size_t)g0 + m) * 256 + t] = f2bf(a);
    }
}

// ---------------------------------------------------------------------------
// Workspace (~64.7 MB total; R1 proved ~70 MB safe, R2 failed at ~72.6):
//   smalls first, then fp32 mats, then bf16 buffers.
//   outp_bf ALIASES xbf (xbf dead after gemm_v; out_pre runs later).
// ---------------------------------------------------------------------------
extern "C" void kernel_launch(void* const* d_in, const int* in_sizes, int n_in,
                              void* d_out, int out_size, void* d_ws, size_t ws_size,
                              hipStream_t stream) {
    const float* query = (const float*)d_in[0];
    const float* Wq = (const float*)d_in[1];
    const float* bq = (const float*)d_in[2];
    const float* Wk = (const float*)d_in[3];
    const float* bk = (const float*)d_in[4];
    const float* Wv = (const float*)d_in[5];
    const float* bv = (const float*)d_in[6];
    const float* Wo = (const float*)d_in[7];
    const float* bo = (const float*)d_in[8];
    float* out = (float*)d_out;

    char* p = (char*)d_ws;
    const size_t SZ_MAT = (size_t)MROWS * 256 * 4;          // 16.78 MB
    float* simq  = (float*)p;            p += (size_t)MROWS * NLM * 4;      // 2.62 MB
    float* simk  = (float*)p;            p += (size_t)MROWS * NLM * 4;      // 2.62 MB
    float* sel   = (float*)p;            p += (size_t)BATCH * NLM * 256 * 4;
    float* tmat  = (float*)p;            p += (size_t)BATCH * NLM * 256 * 4;
    float* xsum  = (float*)p;            p += (size_t)BATCH * 256 * 4;
    float* ws    = (float*)p;            p += (size_t)BATCH * 256 * 4;
    float* score = (float*)p;            p += (size_t)BATCH * SEQ * 4;
    float* q     = (float*)p;            p += SZ_MAT;
    float* k     = (float*)p;            p += SZ_MAT;
    float* v     = (float*)p;            p += SZ_MAT;
    ushort_t* xbf = (ushort_t*)p;        p += (size_t)MROWS * 256 * 2;      // 8.39 MB
    ushort_t* wbf = (ushort_t*)p;        p += (size_t)4 * 256 * 256 * 2;    // 512 KB
    ushort_t* outp_bf = xbf;  // alias: xbf dead after gemm_v

    hipMemsetAsync(xsum, 0, (size_t)BATCH * 256 * 4, stream);
    hipMemsetAsync(tmat, 0, (size_t)BATCH * NLM * 256 * 4, stream);

    const dim3 blk(256);
    const dim3 ggrid(4, MROWS / 128);

    convert_x<<<dim3(MROWS * 256 / 2048), blk, 0, stream>>>(query, xbf);
    convert_w<<<dim3(32, 4), blk, 0, stream>>>(Wq, Wk, Wv, Wo, wbf);
    colsum_kernel<<<dim3(64, BATCH), blk, 0, stream>>>(query, xsum);
    ws_kernel<<<dim3(BATCH), dim3(1024), 0, stream>>>(xsum, Wq, bq, Wk, ws);
    score_kernel<<<dim3(SEQ / 4, BATCH), blk, 0, stream>>>(query, ws, score);

    gemm_bf16<false><<<ggrid, blk, 0, stream>>>(xbf, wbf,           bq, nullptr, q);
    gemm_bf16<false><<<ggrid, blk, 0, stream>>>(xbf, wbf + 65536,   bk, nullptr, k);
    gemm_bf16<false><<<ggrid, blk, 0, stream>>>(xbf, wbf + 131072,  bv, nullptr, v);

    topk_gather<<<dim3(BATCH), dim3(1024), 0, stream>>>(score, k, sel);

    sim_softmax_kernel<<<dim3(SEQ / 64, BATCH), blk, 0, stream>>>(q, sel, simq);
    sim_softmax_kernel<<<dim3(SEQ / 64, BATCH), blk, 0, stream>>>(k, sel, simk);
    tmat_kernel<<<dim3(SEQ / 128, 2, BATCH), blk, 0, stream>>>(simk, v, tmat);

    out_pre_kernel<<<dim3(MROWS / 64), blk, 0, stream>>>(simq, tmat, outp_bf);
    gemm_bf16<true><<<ggrid, blk, 0, stream>>>(outp_bf, wbf + 196608, bo, query, out);
}